// Round 10
// baseline (2795.313 us; speedup 1.0000x reference)
//
#include <hip/hip_runtime.h>
#include <stdint.h>

#define USER_COUNT 100000
#define ITEM_COUNT 50000
#define N_NODES    150000
#define EMB        64
#define N_EDGES    4000000
#define BATCH      4096
#define EPS_F      0.2f
#define NB_SCAN    ((N_NODES + 255) / 256)   // 586

typedef int int4v __attribute__((ext_vector_type(4)));

// ---- JAX threefry-2x32 (20 rounds), bit-exact ----
__host__ __device__ inline void threefry2x32(uint32_t k0, uint32_t k1,
                                             uint32_t& x0, uint32_t& x1) {
  const uint32_t ks2 = k0 ^ k1 ^ 0x1BD11BDAu;
  x0 += k0; x1 += k1;
#define TF_ROT(r) { x0 += x1; x1 = (x1 << (r)) | (x1 >> (32 - (r))); x1 ^= x0; }
  TF_ROT(13) TF_ROT(15) TF_ROT(26) TF_ROT(6)
  x0 += k1;  x1 += ks2 + 1u;
  TF_ROT(17) TF_ROT(29) TF_ROT(16) TF_ROT(24)
  x0 += ks2; x1 += k0 + 2u;
  TF_ROT(13) TF_ROT(15) TF_ROT(26) TF_ROT(6)
  x0 += k0;  x1 += k1 + 3u;
  TF_ROT(17) TF_ROT(29) TF_ROT(16) TF_ROT(24)
  x0 += k1;  x1 += ks2 + 4u;
  TF_ROT(13) TF_ROT(15) TF_ROT(26) TF_ROT(6)
  x0 += ks2; x1 += k0 + 5u;
#undef TF_ROT
}

__global__ void k_zero(int* __restrict__ p, int n) {
  int i = blockIdx.x * blockDim.x + threadIdx.x;
  if (i < n) p[i] = 0;
}

// mirror structure: edges [2M,4M) are edges [0,2M) swapped -> one pass over
// the first half of rows AND cols, two atomics per edge. Same histogram.
__global__ void k_hist(const int* __restrict__ rows, const int* __restrict__ cols,
                       int* __restrict__ deg) {
  const int4v* __restrict__ r4 = (const int4v*)rows;
  const int4v* __restrict__ c4 = (const int4v*)cols;
  int stride = gridDim.x * blockDim.x;
  for (int e = blockIdx.x * blockDim.x + threadIdx.x; e < N_EDGES / 8; e += stride) {
    int4v r = __builtin_nontemporal_load(r4 + e);
    int4v c = __builtin_nontemporal_load(c4 + e);
    atomicAdd(&deg[r.x], 1); atomicAdd(&deg[r.y], 1);
    atomicAdd(&deg[r.z], 1); atomicAdd(&deg[r.w], 1);
    atomicAdd(&deg[c.x], 1); atomicAdd(&deg[c.y], 1);
    atomicAdd(&deg[c.z], 1); atomicAdd(&deg[c.w], 1);
  }
}

// ---- parallel scan over deg: bsum -> bscan -> finalize ----
__global__ void k_bsum(const int* __restrict__ deg, int* __restrict__ bsum) {
  const int i = blockIdx.x * 256 + threadIdx.x;
  const int lane = threadIdx.x & 63, wid = threadIdx.x >> 6;
  int d = (i < N_NODES) ? deg[i] : 0;
#pragma unroll
  for (int s = 32; s; s >>= 1) d += __shfl_down(d, s);
  __shared__ int ws[4];
  if (lane == 0) ws[wid] = d;
  __syncthreads();
  if (threadIdx.x == 0) bsum[blockIdx.x] = ws[0] + ws[1] + ws[2] + ws[3];
}

__global__ void k_bscan(int* __restrict__ bsum, int nb) { // in-place -> exclusive
  const int lane = threadIdx.x; // blockDim = 64
  int carry = 0;
  for (int base = 0; base < nb; base += 64) {
    const int idx = base + lane;
    int v = (idx < nb) ? bsum[idx] : 0;
    int inc = v;
#pragma unroll
    for (int s = 1; s < 64; s <<= 1) { int t = __shfl_up(inc, s); if (lane >= s) inc += t; }
    if (idx < nb) bsum[idx] = inc - v + carry;
    carry += __shfl(inc, 63);
  }
}

__global__ void k_finalize(const int* __restrict__ deg, const int* __restrict__ bsum,
                           int* __restrict__ ptr, float* __restrict__ dis) {
  const int i = blockIdx.x * 256 + threadIdx.x;
  const int lane = threadIdx.x & 63, wid = threadIdx.x >> 6;
  const int d = (i < N_NODES) ? deg[i] : 0;
  int inc = d;
#pragma unroll
  for (int s = 1; s < 64; s <<= 1) { int t = __shfl_up(inc, s); if (lane >= s) inc += t; }
  __shared__ int ws[4];
  if (lane == 63) ws[wid] = inc;
  __syncthreads();
  int woff = bsum[blockIdx.x];
  for (int w = 0; w < wid; ++w) woff += ws[w];
  if (i < N_NODES) {
    ptr[i] = woff + inc - d;                       // exclusive start (scatter cursor)
    dis[i] = 1.0f / sqrtf((float)(d > 0 ? d : 1));
  }
}

// XCD-team scatter (R6, proven): teams 0-3 own user-node ranges, stream edges
// [0,2M); teams 4-7 own item-node ranges, stream edges [2M,4M). Write/atomic
// locality per XCD is what matters (R9: dropping teams doubled time).
__global__ void k_scatter(const int* __restrict__ rows, const int* __restrict__ cols,
                          int* __restrict__ ptr, int* __restrict__ ecol) {
  const int team = blockIdx.x & 7;
  const int tb   = blockIdx.x >> 3;
  const int nTb  = gridDim.x >> 3;
  const bool userTeam = team < 4;
  const int lo = userTeam ? team * (USER_COUNT / 4)
                          : USER_COUNT + (team - 4) * (ITEM_COUNT / 4);
  const int hi = lo + (userTeam ? USER_COUNT / 4 : ITEM_COUNT / 4);
  const int ebase = userTeam ? 0 : N_EDGES / 2;
  const int stride = nTb * blockDim.x;
  for (int e = tb * blockDim.x + threadIdx.x; e < N_EDGES / 2; e += stride) {
    const int idx = ebase + e;
    const int r = __builtin_nontemporal_load(rows + idx);
    if (r >= lo && r < hi) {
      const int c = __builtin_nontemporal_load(cols + idx);
      int pos = atomicAdd(&ptr[r], 1);
      ecol[pos] = c;
    }
  }
}

// Z0 = dis * concat(user_emb, item_emb), float4-wide
__global__ __launch_bounds__(256) void k_init(const float* __restrict__ ue,
                                              const float* __restrict__ ie,
                                              const float* __restrict__ dis,
                                              float* __restrict__ Z) {
  const int idx = blockIdx.x * blockDim.x + threadIdx.x; // float4 index
  if (idx >= N_NODES * 16) return;
  float4 v = (idx < USER_COUNT * 16) ? ((const float4*)ue)[idx]
                                     : ((const float4*)ie)[idx - USER_COUNT * 16];
  const float d = dis[idx >> 4];
  v.x *= d; v.y *= d; v.z *= d; v.w *= d;
  ((float4*)Z)[idx] = v;
}

// Dimension-split spmm: blockIdx = rc*8 + db; db (dim-block, dims 8db..8db+8)
// lands on XCD db via round-robin -> each XCD's Z gather slice is 4.8MB,
// ~L2-resident, reused deg(c)~27 times. Wave = 8 octets; octet owns one row;
// each lane owns whole edges (32B = 8 dims), 4 edge slots in flight per lane.
// CLEAN=1: Zout = dis^2 * sum (clean layer). CLEAN=0: Zout = raw sum (noise
// kernel applies dis/noise full-width afterwards; norm needs all 64 dims).
template <int CLEAN>
__global__ __launch_bounds__(256) void k_spmm_ds(const int* __restrict__ ptr,
                                                 const int* __restrict__ ecol,
                                                 const float* __restrict__ dis,
                                                 const float* __restrict__ Z,
                                                 float* __restrict__ Zout) {
  const int db = blockIdx.x & 7;
  const int rc = blockIdx.x >> 3;
  const int lane = threadIdx.x & 63;
  const int oct = lane >> 3;      // octet 0..7 -> row within wave
  const int k   = lane & 7;       // edge phase within octet
  const int w = rc * 32 + (threadIdx.x >> 6) * 8 + oct;
  if (w >= N_NODES) return;
  const int e1 = ptr[w];                  // end (cursor after scatter)
  const int e0 = (w > 0) ? ptr[w - 1] : 0;

  float a0=0.f,a1=0.f,a2=0.f,a3=0.f,a4=0.f,a5=0.f,a6=0.f,a7=0.f;
  for (int j = e0; j < e1; j += 32) {
    int  cc[4];
    bool ok[4];
#pragma unroll
    for (int s = 0; s < 4; ++s) {
      const int js = j + 8 * s + k;
      ok[s] = js < e1;
      cc[s] = __builtin_nontemporal_load(ecol + (ok[s] ? js : e0));
    }
    float4 xa[4], xb[4];
#pragma unroll
    for (int s = 0; s < 4; ++s) {
      const float4* p = (const float4*)(Z + (size_t)cc[s] * EMB + db * 8);
      xa[s] = p[0]; xb[s] = p[1];
    }
#pragma unroll
    for (int s = 0; s < 4; ++s) {
      const float m = ok[s] ? 1.f : 0.f;
      a0 = fmaf(m, xa[s].x, a0); a1 = fmaf(m, xa[s].y, a1);
      a2 = fmaf(m, xa[s].z, a2); a3 = fmaf(m, xa[s].w, a3);
      a4 = fmaf(m, xb[s].x, a4); a5 = fmaf(m, xb[s].y, a5);
      a6 = fmaf(m, xb[s].z, a6); a7 = fmaf(m, xb[s].w, a7);
    }
  }
  // reduce across the 8 lanes of the octet (xor 1,2,4 stay within octet)
#pragma unroll
  for (int s = 1; s < 8; s <<= 1) {
    a0 += __shfl_xor(a0, s); a1 += __shfl_xor(a1, s);
    a2 += __shfl_xor(a2, s); a3 += __shfl_xor(a3, s);
    a4 += __shfl_xor(a4, s); a5 += __shfl_xor(a5, s);
    a6 += __shfl_xor(a6, s); a7 += __shfl_xor(a7, s);
  }
  if (k == 0) {
    float sc = 1.0f;
    if (CLEAN) { const float dw = dis[w]; sc = dw * dw; }
    float4 r0; r0.x = a0*sc; r0.y = a1*sc; r0.z = a2*sc; r0.w = a3*sc;
    float4 r1; r1.x = a4*sc; r1.y = a5*sc; r1.z = a6*sc; r1.w = a7*sc;
    float4* o = (float4*)(Zout + (size_t)w * EMB + db * 8);
    o[0] = r0; o[1] = r1;
  }
}

// full-width noise: in-place S -> Z. ego = dw*S; ego += sign(ego)*u*eps/||u||;
// Z = dw*ego. lane = dim.
__global__ __launch_bounds__(256) void k_noise(float* __restrict__ S,
                                               const float* __restrict__ dis,
                                               uint32_t k0, uint32_t k1) {
  const int w = (blockIdx.x * blockDim.x + threadIdx.x) >> 6;
  const int lane = threadIdx.x & 63;
  if (w >= N_NODES) return;
  const float dw = dis[w];
  float v = dw * S[(size_t)w * EMB + lane];
  uint32_t t0 = 0u, t1 = (uint32_t)(w * EMB + lane);
  threefry2x32(k0, k1, t0, t1);
  const uint32_t bits = t0 ^ t1;
  const float u = __uint_as_float((bits >> 9) | 0x3f800000u) - 1.0f;
  float ss = u * u;
#pragma unroll
  for (int s = 1; s < 64; s <<= 1) ss += __shfl_xor(ss, s);
  const float inv = 1.0f / fmaxf(sqrtf(ss), 1e-12f);
  const float sg = (v > 0.f) ? 1.f : ((v < 0.f) ? -1.f : 0.f);
  v = fmaf(sg * u, EPS_F * inv, v);
  S[(size_t)w * EMB + lane] = dw * v;
}

// gather batch rows from Z, recovering ego = Z * sqrt(max(deg,1));
// optional second (cl) destination at scale 1
__global__ __launch_bounds__(256) void k_gather(const float* __restrict__ Z,
                                                const int* __restrict__ deg,
                                                const int* __restrict__ users,
                                                const int* __restrict__ items,
                                                float* __restrict__ out_u,
                                                float* __restrict__ out_i,
                                                float* __restrict__ cl_u,
                                                float* __restrict__ cl_i,
                                                float scale, int init) {
  const int w = (blockIdx.x * blockDim.x + threadIdx.x) >> 6;
  const int lane = threadIdx.x & 63;
  if (w >= 2 * BATCH) return;
  int src; float* dst; float* dst2;
  if (w < BATCH) {
    src = users[w];               dst = out_u + w * EMB;
    dst2 = cl_u ? cl_u + w * EMB : nullptr;
  } else {
    int q = w - BATCH;
    src = USER_COUNT + items[q];  dst = out_i + q * EMB;
    dst2 = cl_i ? cl_i + q * EMB : nullptr;
  }
  const int d = deg[src];
  const float rdis = sqrtf((float)(d > 0 ? d : 1));
  float raw = Z[(size_t)src * EMB + lane] * rdis;
  float v = raw * scale;
  dst[lane] = init ? v : (dst[lane] + v);
  if (dst2) dst2[lane] = raw;
}

extern "C" void kernel_launch(void* const* d_in, const int* in_sizes, int n_in,
                              void* d_out, int out_size, void* d_ws, size_t ws_size,
                              hipStream_t stream) {
  const float* user_emb = (const float*)d_in[0];
  const float* item_emb = (const float*)d_in[1];
  // d_in[2] = vals: unused, recomputed bit-identically from degrees
  const int* rows  = (const int*)d_in[3];
  const int* cols  = (const int*)d_in[4];
  const int* users = (const int*)d_in[5];
  const int* items = (const int*)d_in[6];

  float* X   = (float*)d_ws;                       // 9.6M f32 (Z ping)
  float* Y   = X + (size_t)N_NODES * EMB;          // 9.6M f32 (Z pong)
  int*   deg = (int*)(Y + (size_t)N_NODES * EMB);  // 150k
  int*   ptr = deg + N_NODES;                      // 150k
  float* dis = (float*)(ptr + N_NODES);            // 150k
  int*   ecol = (int*)(dis + N_NODES);             // 4M
  int*   bsum = ecol + N_EDGES;                    // 586

  float* out  = (float*)d_out;
  float* u_all = out;
  float* i_all = out + (size_t)BATCH * EMB;
  float* u_tr  = out + (size_t)2 * BATCH * EMB;
  float* i_tr  = out + (size_t)3 * BATCH * EMB;
  float* u_cl  = out + (size_t)4 * BATCH * EMB;
  float* i_cl  = out + (size_t)5 * BATCH * EMB;

  // ---- build CSR (per launch, deterministic work) ----
  k_zero<<<NB_SCAN, 256, 0, stream>>>(deg, N_NODES);
  k_hist<<<1024, 256, 0, stream>>>(rows, cols, deg);
  k_bsum<<<NB_SCAN, 256, 0, stream>>>(deg, bsum);
  k_bscan<<<1, 64, 0, stream>>>(bsum, NB_SCAN);
  k_finalize<<<NB_SCAN, 256, 0, stream>>>(deg, bsum, ptr, dis);
  k_scatter<<<2048, 256, 0, stream>>>(rows, cols, ptr, ecol);

  // ---- Z0 = dis * concat(user_emb, item_emb) ----
  k_init<<<(N_NODES * 16 + 255) / 256, 256, 0, stream>>>(user_emb, item_emb, dis, X);

  const int nrc = (N_NODES + 31) / 32;               // row chunks of 32
  const int spmm_grid = nrc * 8;                     // x 8 dim-blocks = 37504
  const int noise_grid = (N_NODES * EMB + 255) / 256; // 37500
  const int gat_grid  = (2 * BATCH * EMB + 255) / 256; // 2048

  // ---- phase 1: 3 clean layers, mean-gather into outputs 0,1 ----
  for (int l = 0; l < 3; ++l) {
    k_spmm_ds<1><<<spmm_grid, 256, 0, stream>>>(ptr, ecol, dis, X, Y);
    k_gather<<<gat_grid, 256, 0, stream>>>(Y, deg, users, items, u_all, i_all,
                                           nullptr, nullptr, 1.0f / 3.0f, l == 0);
    float* t = X; X = Y; Y = t;
  }

  // ---- phase 2: 3 noisy layers (raw spmm, then full-width noise in place) ----
  for (int k = 0; k < 3; ++k) {
    uint32_t f0 = 0u, f1 = (uint32_t)k;      // fold_in(key(42), k)
    threefry2x32(0u, 42u, f0, f1);
    k_spmm_ds<0><<<spmm_grid, 256, 0, stream>>>(ptr, ecol, dis, X, Y);
    k_noise<<<noise_grid, 256, 0, stream>>>(Y, dis, f0, f1);
    k_gather<<<gat_grid, 256, 0, stream>>>(Y, deg, users, items, u_tr, i_tr,
                                           (k == 0) ? u_cl : nullptr,
                                           (k == 0) ? i_cl : nullptr,
                                           1.0f / 3.0f, k == 0);
    float* t = X; X = Y; Y = t;
  }
}

// Round 11
// 1102.029 us; speedup vs baseline: 2.5365x; 2.5365x over previous
//
#include <hip/hip_runtime.h>
#include <stdint.h>

#define USER_COUNT 100000
#define ITEM_COUNT 50000
#define N_NODES    150000
#define EMB        64
#define N_EDGES    4000000
#define BATCH      4096
#define EPS_F      0.2f
#define NB_SCAN    ((N_NODES + 255) / 256)   // 586

typedef int int4v __attribute__((ext_vector_type(4)));

// ---- JAX threefry-2x32 (20 rounds), bit-exact ----
__host__ __device__ inline void threefry2x32(uint32_t k0, uint32_t k1,
                                             uint32_t& x0, uint32_t& x1) {
  const uint32_t ks2 = k0 ^ k1 ^ 0x1BD11BDAu;
  x0 += k0; x1 += k1;
#define TF_ROT(r) { x0 += x1; x1 = (x1 << (r)) | (x1 >> (32 - (r))); x1 ^= x0; }
  TF_ROT(13) TF_ROT(15) TF_ROT(26) TF_ROT(6)
  x0 += k1;  x1 += ks2 + 1u;
  TF_ROT(17) TF_ROT(29) TF_ROT(16) TF_ROT(24)
  x0 += ks2; x1 += k0 + 2u;
  TF_ROT(13) TF_ROT(15) TF_ROT(26) TF_ROT(6)
  x0 += k0;  x1 += k1 + 3u;
  TF_ROT(17) TF_ROT(29) TF_ROT(16) TF_ROT(24)
  x0 += k1;  x1 += ks2 + 4u;
  TF_ROT(13) TF_ROT(15) TF_ROT(26) TF_ROT(6)
  x0 += ks2; x1 += k0 + 5u;
#undef TF_ROT
}

// mirror structure: edges [2M,4M) are edges [0,2M) swapped -> one pass over
// the first half of rows AND cols, two atomics per edge. Same histogram.
__global__ void k_hist(const int* __restrict__ rows, const int* __restrict__ cols,
                       int* __restrict__ deg) {
  const int4v* __restrict__ r4 = (const int4v*)rows;
  const int4v* __restrict__ c4 = (const int4v*)cols;
  int stride = gridDim.x * blockDim.x;
  for (int e = blockIdx.x * blockDim.x + threadIdx.x; e < N_EDGES / 8; e += stride) {
    int4v r = __builtin_nontemporal_load(r4 + e);
    int4v c = __builtin_nontemporal_load(c4 + e);
    atomicAdd(&deg[r.x], 1); atomicAdd(&deg[r.y], 1);
    atomicAdd(&deg[r.z], 1); atomicAdd(&deg[r.w], 1);
    atomicAdd(&deg[c.x], 1); atomicAdd(&deg[c.y], 1);
    atomicAdd(&deg[c.z], 1); atomicAdd(&deg[c.w], 1);
  }
}

// ---- parallel scan over deg: bsum -> bscan -> finalize ----
__global__ void k_bsum(const int* __restrict__ deg, int* __restrict__ bsum) {
  const int i = blockIdx.x * 256 + threadIdx.x;
  const int lane = threadIdx.x & 63, wid = threadIdx.x >> 6;
  int d = (i < N_NODES) ? deg[i] : 0;
#pragma unroll
  for (int s = 32; s; s >>= 1) d += __shfl_down(d, s);
  __shared__ int ws[4];
  if (lane == 0) ws[wid] = d;
  __syncthreads();
  if (threadIdx.x == 0) bsum[blockIdx.x] = ws[0] + ws[1] + ws[2] + ws[3];
}

__global__ void k_bscan(int* __restrict__ bsum, int nb) { // in-place -> exclusive
  const int lane = threadIdx.x; // blockDim = 64
  int carry = 0;
  for (int base = 0; base < nb; base += 64) {
    const int idx = base + lane;
    int v = (idx < nb) ? bsum[idx] : 0;
    int inc = v;
#pragma unroll
    for (int s = 1; s < 64; s <<= 1) { int t = __shfl_up(inc, s); if (lane >= s) inc += t; }
    if (idx < nb) bsum[idx] = inc - v + carry;
    carry += __shfl(inc, 63);
  }
}

__global__ void k_finalize(const int* __restrict__ deg, const int* __restrict__ bsum,
                           int* __restrict__ ptr, float* __restrict__ dis) {
  const int i = blockIdx.x * 256 + threadIdx.x;
  const int lane = threadIdx.x & 63, wid = threadIdx.x >> 6;
  const int d = (i < N_NODES) ? deg[i] : 0;
  int inc = d;
#pragma unroll
  for (int s = 1; s < 64; s <<= 1) { int t = __shfl_up(inc, s); if (lane >= s) inc += t; }
  __shared__ int ws[4];
  if (lane == 63) ws[wid] = inc;
  __syncthreads();
  int woff = bsum[blockIdx.x];
  for (int w = 0; w < wid; ++w) woff += ws[w];
  if (i < N_NODES) {
    ptr[i] = woff + inc - d;                       // exclusive start (scatter cursor)
    dis[i] = 1.0f / sqrtf((float)(d > 0 ? d : 1));
  }
}

// XCD-team scatter (R6 structure, proven 180us) + 4-wide independent
// edge-chains per thread (MLP on the load->atomic->store chain).
// teams 0-3 own user-node ranges (stream edges [0,2M), user rows);
// teams 4-7 own item-node ranges (stream edges [2M,4M), item rows).
__global__ void k_scatter(const int* __restrict__ rows, const int* __restrict__ cols,
                          int* __restrict__ ptr, int* __restrict__ ecol) {
  const int team = blockIdx.x & 7;
  const int tb   = blockIdx.x >> 3;
  const int nTb  = gridDim.x >> 3;             // 256
  const bool userTeam = team < 4;
  const int lo = userTeam ? team * (USER_COUNT / 4)
                          : USER_COUNT + (team - 4) * (ITEM_COUNT / 4);
  const int hi = lo + (userTeam ? USER_COUNT / 4 : ITEM_COUNT / 4);
  const int ebase = userTeam ? 0 : N_EDGES / 2;
  const int tstride = nTb * blockDim.x;        // 65536
  const int t0 = tb * blockDim.x + threadIdx.x;
  for (int j = t0; j < N_EDGES / 2; j += 4 * tstride) {
    int r[4], c[4]; bool v[4];
#pragma unroll
    for (int q = 0; q < 4; ++q) {
      const int e = j + q * tstride;
      v[q] = e < N_EDGES / 2;
      const int idx = ebase + (v[q] ? e : j);
      r[q] = __builtin_nontemporal_load(rows + idx);
      c[q] = __builtin_nontemporal_load(cols + idx);
    }
#pragma unroll
    for (int q = 0; q < 4; ++q) {
      if (v[q] && r[q] >= lo && r[q] < hi) {
        int pos = atomicAdd(&ptr[r[q]], 1);
        ecol[pos] = c[q];
      }
    }
  }
}

// Z0 = dis * concat(user_emb, item_emb), float4-wide
__global__ __launch_bounds__(256) void k_init(const float* __restrict__ ue,
                                              const float* __restrict__ ie,
                                              const float* __restrict__ dis,
                                              float* __restrict__ Z) {
  const int idx = blockIdx.x * blockDim.x + threadIdx.x; // float4 index
  if (idx >= N_NODES * 16) return;
  float4 v = (idx < USER_COUNT * 16) ? ((const float4*)ue)[idx]
                                     : ((const float4*)ie)[idx - USER_COUNT * 16];
  const float d = dis[idx >> 4];
  v.x *= d; v.y *= d; v.z *= d; v.w *= d;
  ((float4*)Z)[idx] = v;
}

// One wave per output row, Z-iteration: acc = sum_{c in N(r)} Z[c] (pure
// gather-sum). 4 groups x 16 lanes x float4; 8 slots/lane -> 32 independent
// Z-row gathers in flight per wave. fp32 throughout (sign(ego) is
// discontinuous: narrow-Z variants flip noise signs and fail — R8).
// All shapes tried (R4/R7/R10) plateau at ~3.3 TB/s L2-fill: random-gather
// fabric ceiling; time ~= FETCH / 3.3 TB/s.
template <int NOISE>
__global__ __launch_bounds__(256) void k_spmm(const int* __restrict__ ptr,
                                              const int* __restrict__ ecol,
                                              const float* __restrict__ dis,
                                              const float* __restrict__ Z,
                                              float* __restrict__ Zout,
                                              uint32_t k0, uint32_t k1) {
  const int w = (blockIdx.x * blockDim.x + threadIdx.x) >> 6;
  const int lane = threadIdx.x & 63;
  if (w >= N_NODES) return;
  const int g   = lane >> 4;   // edge-slot group 0..3
  const int sub = lane & 15;   // dim block: dims [sub*4, sub*4+4)
  const int e1 = ptr[w];                  // end (cursor after scatter)
  const int e0 = (w > 0) ? ptr[w - 1] : 0;
  const float4* __restrict__ Z4 = (const float4*)Z;

  float ax = 0.f, ay = 0.f, az = 0.f, aq = 0.f;
  for (int j = e0 + g; j < e1; j += 32) {
    int  cc[8];
    bool ok[8];
#pragma unroll
    for (int s = 0; s < 8; ++s) {
      const int js = j + 4 * s;
      ok[s] = js < e1;
      cc[s] = __builtin_nontemporal_load(ecol + (ok[s] ? js : j));
    }
    float4 xv[8];
#pragma unroll
    for (int s = 0; s < 8; ++s) xv[s] = Z4[cc[s] * 16 + sub];
#pragma unroll
    for (int s = 0; s < 8; ++s) {
      const float m = ok[s] ? 1.f : 0.f;
      ax = fmaf(m, xv[s].x, ax); ay = fmaf(m, xv[s].y, ay);
      az = fmaf(m, xv[s].z, az); aq = fmaf(m, xv[s].w, aq);
    }
  }
  // reduce across the 4 edge-slot groups
  ax += __shfl_xor(ax, 16); ax += __shfl_xor(ax, 32);
  ay += __shfl_xor(ay, 16); ay += __shfl_xor(ay, 32);
  az += __shfl_xor(az, 16); az += __shfl_xor(az, 32);
  aq += __shfl_xor(aq, 16); aq += __shfl_xor(aq, 32);

  const float dw = dis[w];
  float z0, z1, z2, z3;
  if (NOISE) {
    // ego = dw * acc; ego += sign(ego)*u*eps/||n||; Zout = dw * ego
    float v0 = dw * ax, v1 = dw * ay, v2 = dw * az, v3 = dw * aq;
    uint32_t t0 = 0u, t1 = (uint32_t)(w * EMB + sub * 4 + g);
    threefry2x32(k0, k1, t0, t1);
    const uint32_t bits = t0 ^ t1;
    const float u = __uint_as_float((bits >> 9) | 0x3f800000u) - 1.0f;
    float ss = u * u;
#pragma unroll
    for (int s = 1; s < 64; s <<= 1) ss += __shfl_xor(ss, s);
    const float inv = 1.0f / fmaxf(sqrtf(ss), 1e-12f);
    const float u0 = __shfl(u, sub);
    const float u1 = __shfl(u, 16 + sub);
    const float u2 = __shfl(u, 32 + sub);
    const float u3 = __shfl(u, 48 + sub);
    const float e = EPS_F * inv;
    v0 = fmaf(((v0 > 0.f) ? 1.f : ((v0 < 0.f) ? -1.f : 0.f)) * u0, e, v0);
    v1 = fmaf(((v1 > 0.f) ? 1.f : ((v1 < 0.f) ? -1.f : 0.f)) * u1, e, v1);
    v2 = fmaf(((v2 > 0.f) ? 1.f : ((v2 < 0.f) ? -1.f : 0.f)) * u2, e, v2);
    v3 = fmaf(((v3 > 0.f) ? 1.f : ((v3 < 0.f) ? -1.f : 0.f)) * u3, e, v3);
    z0 = dw * v0; z1 = dw * v1; z2 = dw * v2; z3 = dw * v3;
  } else {
    const float d2 = dw * dw;
    z0 = d2 * ax; z1 = d2 * ay; z2 = d2 * az; z3 = d2 * aq;
  }
  if (g == 0) {
    float4 r; r.x = z0; r.y = z1; r.z = z2; r.w = z3;
    ((float4*)Zout)[w * 16 + sub] = r;
  }
}

// gather batch rows from Z, recovering ego = Z * sqrt(max(deg,1));
// optional second (cl) destination at scale 1
__global__ __launch_bounds__(256) void k_gather(const float* __restrict__ Z,
                                                const int* __restrict__ deg,
                                                const int* __restrict__ users,
                                                const int* __restrict__ items,
                                                float* __restrict__ out_u,
                                                float* __restrict__ out_i,
                                                float* __restrict__ cl_u,
                                                float* __restrict__ cl_i,
                                                float scale, int init) {
  const int w = (blockIdx.x * blockDim.x + threadIdx.x) >> 6;
  const int lane = threadIdx.x & 63;
  if (w >= 2 * BATCH) return;
  int src; float* dst; float* dst2;
  if (w < BATCH) {
    src = users[w];               dst = out_u + w * EMB;
    dst2 = cl_u ? cl_u + w * EMB : nullptr;
  } else {
    int q = w - BATCH;
    src = USER_COUNT + items[q];  dst = out_i + q * EMB;
    dst2 = cl_i ? cl_i + q * EMB : nullptr;
  }
  const int d = deg[src];
  const float rdis = sqrtf((float)(d > 0 ? d : 1));
  float raw = Z[(size_t)src * EMB + lane] * rdis;
  float v = raw * scale;
  dst[lane] = init ? v : (dst[lane] + v);
  if (dst2) dst2[lane] = raw;
}

extern "C" void kernel_launch(void* const* d_in, const int* in_sizes, int n_in,
                              void* d_out, int out_size, void* d_ws, size_t ws_size,
                              hipStream_t stream) {
  const float* user_emb = (const float*)d_in[0];
  const float* item_emb = (const float*)d_in[1];
  // d_in[2] = vals: unused, recomputed bit-identically from degrees
  const int* rows  = (const int*)d_in[3];
  const int* cols  = (const int*)d_in[4];
  const int* users = (const int*)d_in[5];
  const int* items = (const int*)d_in[6];

  float* X   = (float*)d_ws;                       // 9.6M f32 (Z ping)
  float* Y   = X + (size_t)N_NODES * EMB;          // 9.6M f32 (Z pong)
  int*   deg = (int*)(Y + (size_t)N_NODES * EMB);  // 150k
  int*   ptr = deg + N_NODES;                      // 150k
  float* dis = (float*)(ptr + N_NODES);            // 150k
  int*   ecol = (int*)(dis + N_NODES);             // 4M
  int*   bsum = ecol + N_EDGES;                    // 586

  float* out  = (float*)d_out;
  float* u_all = out;
  float* i_all = out + (size_t)BATCH * EMB;
  float* u_tr  = out + (size_t)2 * BATCH * EMB;
  float* i_tr  = out + (size_t)3 * BATCH * EMB;
  float* u_cl  = out + (size_t)4 * BATCH * EMB;
  float* i_cl  = out + (size_t)5 * BATCH * EMB;

  // ---- build CSR (per launch, deterministic work) ----
  hipMemsetAsync(deg, 0, sizeof(int) * N_NODES, stream);
  k_hist<<<1024, 256, 0, stream>>>(rows, cols, deg);
  k_bsum<<<NB_SCAN, 256, 0, stream>>>(deg, bsum);
  k_bscan<<<1, 64, 0, stream>>>(bsum, NB_SCAN);
  k_finalize<<<NB_SCAN, 256, 0, stream>>>(deg, bsum, ptr, dis);
  k_scatter<<<2048, 256, 0, stream>>>(rows, cols, ptr, ecol);

  // ---- Z0 = dis * concat(user_emb, item_emb) ----
  k_init<<<(N_NODES * 16 + 255) / 256, 256, 0, stream>>>(user_emb, item_emb, dis, X);

  const int spmm_grid = (N_NODES * EMB + 255) / 256; // 37500
  const int gat_grid  = (2 * BATCH * EMB + 255) / 256; // 2048

  // ---- phase 1: 3 clean layers, mean-gather into outputs 0,1 ----
  for (int l = 0; l < 3; ++l) {
    k_spmm<0><<<spmm_grid, 256, 0, stream>>>(ptr, ecol, dis, X, Y, 0u, 0u);
    k_gather<<<gat_grid, 256, 0, stream>>>(Y, deg, users, items, u_all, i_all,
                                           nullptr, nullptr, 1.0f / 3.0f, l == 0);
    float* t = X; X = Y; Y = t;
  }

  // ---- phase 2: 3 noisy layers (noise fused into spmm epilogue) ----
  for (int k = 0; k < 3; ++k) {
    uint32_t f0 = 0u, f1 = (uint32_t)k;      // fold_in(key(42), k)
    threefry2x32(0u, 42u, f0, f1);
    k_spmm<1><<<spmm_grid, 256, 0, stream>>>(ptr, ecol, dis, X, Y, f0, f1);
    k_gather<<<gat_grid, 256, 0, stream>>>(Y, deg, users, items, u_tr, i_tr,
                                           (k == 0) ? u_cl : nullptr,
                                           (k == 0) ? i_cl : nullptr,
                                           1.0f / 3.0f, k == 0);
    float* t = X; X = Y; Y = t;
  }
}

// Round 12
// 991.089 us; speedup vs baseline: 2.8204x; 1.1119x over previous
//
#include <hip/hip_runtime.h>
#include <stdint.h>

#define USER_COUNT 100000
#define ITEM_COUNT 50000
#define N_NODES    150000
#define EMB        64
#define N_EDGES    4000000
#define BATCH      4096
#define EPS_F      0.2f
#define NB_SCAN    ((N_NODES + 255) / 256)   // 586

typedef int int4v __attribute__((ext_vector_type(4)));

// ---- JAX threefry-2x32 (20 rounds), bit-exact ----
__host__ __device__ inline void threefry2x32(uint32_t k0, uint32_t k1,
                                             uint32_t& x0, uint32_t& x1) {
  const uint32_t ks2 = k0 ^ k1 ^ 0x1BD11BDAu;
  x0 += k0; x1 += k1;
#define TF_ROT(r) { x0 += x1; x1 = (x1 << (r)) | (x1 >> (32 - (r))); x1 ^= x0; }
  TF_ROT(13) TF_ROT(15) TF_ROT(26) TF_ROT(6)
  x0 += k1;  x1 += ks2 + 1u;
  TF_ROT(17) TF_ROT(29) TF_ROT(16) TF_ROT(24)
  x0 += ks2; x1 += k0 + 2u;
  TF_ROT(13) TF_ROT(15) TF_ROT(26) TF_ROT(6)
  x0 += k0;  x1 += k1 + 3u;
  TF_ROT(17) TF_ROT(29) TF_ROT(16) TF_ROT(24)
  x0 += k1;  x1 += ks2 + 4u;
  TF_ROT(13) TF_ROT(15) TF_ROT(26) TF_ROT(6)
  x0 += ks2; x1 += k0 + 5u;
#undef TF_ROT
}

// mirror structure: edges [2M,4M) are edges [0,2M) swapped -> one pass over
// the first half of rows AND cols, two atomics per edge. Same histogram.
__global__ void k_hist(const int* __restrict__ rows, const int* __restrict__ cols,
                       int* __restrict__ deg) {
  const int4v* __restrict__ r4 = (const int4v*)rows;
  const int4v* __restrict__ c4 = (const int4v*)cols;
  int stride = gridDim.x * blockDim.x;
  for (int e = blockIdx.x * blockDim.x + threadIdx.x; e < N_EDGES / 8; e += stride) {
    int4v r = __builtin_nontemporal_load(r4 + e);
    int4v c = __builtin_nontemporal_load(c4 + e);
    atomicAdd(&deg[r.x], 1); atomicAdd(&deg[r.y], 1);
    atomicAdd(&deg[r.z], 1); atomicAdd(&deg[r.w], 1);
    atomicAdd(&deg[c.x], 1); atomicAdd(&deg[c.y], 1);
    atomicAdd(&deg[c.z], 1); atomicAdd(&deg[c.w], 1);
  }
}

// ---- parallel scan over deg: bsum -> bscan -> finalize ----
__global__ void k_bsum(const int* __restrict__ deg, int* __restrict__ bsum) {
  const int i = blockIdx.x * 256 + threadIdx.x;
  const int lane = threadIdx.x & 63, wid = threadIdx.x >> 6;
  int d = (i < N_NODES) ? deg[i] : 0;
#pragma unroll
  for (int s = 32; s; s >>= 1) d += __shfl_down(d, s);
  __shared__ int ws[4];
  if (lane == 0) ws[wid] = d;
  __syncthreads();
  if (threadIdx.x == 0) bsum[blockIdx.x] = ws[0] + ws[1] + ws[2] + ws[3];
}

__global__ void k_bscan(int* __restrict__ bsum, int nb) { // in-place -> exclusive
  const int lane = threadIdx.x; // blockDim = 64
  int carry = 0;
  for (int base = 0; base < nb; base += 64) {
    const int idx = base + lane;
    int v = (idx < nb) ? bsum[idx] : 0;
    int inc = v;
#pragma unroll
    for (int s = 1; s < 64; s <<= 1) { int t = __shfl_up(inc, s); if (lane >= s) inc += t; }
    if (idx < nb) bsum[idx] = inc - v + carry;
    carry += __shfl(inc, 63);
  }
}

__global__ void k_finalize(const int* __restrict__ deg, const int* __restrict__ bsum,
                           int* __restrict__ ptr, float* __restrict__ dis) {
  const int i = blockIdx.x * 256 + threadIdx.x;
  const int lane = threadIdx.x & 63, wid = threadIdx.x >> 6;
  const int d = (i < N_NODES) ? deg[i] : 0;
  int inc = d;
#pragma unroll
  for (int s = 1; s < 64; s <<= 1) { int t = __shfl_up(inc, s); if (lane >= s) inc += t; }
  __shared__ int ws[4];
  if (lane == 63) ws[wid] = inc;
  __syncthreads();
  int woff = bsum[blockIdx.x];
  for (int w = 0; w < wid; ++w) woff += ws[w];
  if (i < N_NODES) {
    ptr[i] = woff + inc - d;                       // exclusive start (scatter cursor)
    dis[i] = 1.0f / sqrtf((float)(d > 0 ? d : 1));
  }
}

// XCD-team scatter (R6/R11, proven 179us; atomic-locality on ptr slices is
// the binding constraint — R9 without teams doubled time).
__global__ void k_scatter(const int* __restrict__ rows, const int* __restrict__ cols,
                          int* __restrict__ ptr, int* __restrict__ ecol) {
  const int team = blockIdx.x & 7;
  const int tb   = blockIdx.x >> 3;
  const int nTb  = gridDim.x >> 3;             // 256
  const bool userTeam = team < 4;
  const int lo = userTeam ? team * (USER_COUNT / 4)
                          : USER_COUNT + (team - 4) * (ITEM_COUNT / 4);
  const int hi = lo + (userTeam ? USER_COUNT / 4 : ITEM_COUNT / 4);
  const int ebase = userTeam ? 0 : N_EDGES / 2;
  const int tstride = nTb * blockDim.x;        // 65536
  const int t0 = tb * blockDim.x + threadIdx.x;
  for (int j = t0; j < N_EDGES / 2; j += 4 * tstride) {
    int r[4], c[4]; bool v[4];
#pragma unroll
    for (int q = 0; q < 4; ++q) {
      const int e = j + q * tstride;
      v[q] = e < N_EDGES / 2;
      const int idx = ebase + (v[q] ? e : j);
      r[q] = __builtin_nontemporal_load(rows + idx);
      c[q] = __builtin_nontemporal_load(cols + idx);
    }
#pragma unroll
    for (int q = 0; q < 4; ++q) {
      if (v[q] && r[q] >= lo && r[q] < hi) {
        int pos = atomicAdd(&ptr[r[q]], 1);
        ecol[pos] = c[q];
      }
    }
  }
}

// Z0 = dis * concat(user_emb, item_emb), float4-wide
__global__ __launch_bounds__(256) void k_init(const float* __restrict__ ue,
                                              const float* __restrict__ ie,
                                              const float* __restrict__ dis,
                                              float* __restrict__ Z) {
  const int idx = blockIdx.x * blockDim.x + threadIdx.x; // float4 index
  if (idx >= N_NODES * 16) return;
  float4 v = (idx < USER_COUNT * 16) ? ((const float4*)ue)[idx]
                                     : ((const float4*)ie)[idx - USER_COUNT * 16];
  const float d = dis[idx >> 4];
  v.x *= d; v.y *= d; v.z *= d; v.w *= d;
  ((float4*)Z)[idx] = v;
}

// One wave per output row, Z-iteration: acc = sum_{c in N(r)} Z[c] (pure
// gather-sum). 4 groups x 16 lanes x float4; 8 slots/lane -> 32 independent
// Z-row gathers in flight per wave. fp32 throughout (sign(ego) is
// discontinuous: narrow-Z variants flip noise signs and fail — R8).
// All shapes tried (R4/R7/R10) plateau at ~3.3 TB/s L2-fill: random-gather
// fabric ceiling; time ~= FETCH / 3.3 TB/s.
template <int NOISE>
__global__ __launch_bounds__(256) void k_spmm(const int* __restrict__ ptr,
                                              const int* __restrict__ ecol,
                                              const float* __restrict__ dis,
                                              const float* __restrict__ Z,
                                              float* __restrict__ Zout,
                                              uint32_t k0, uint32_t k1) {
  const int w = (blockIdx.x * blockDim.x + threadIdx.x) >> 6;
  const int lane = threadIdx.x & 63;
  if (w >= N_NODES) return;
  const int g   = lane >> 4;   // edge-slot group 0..3
  const int sub = lane & 15;   // dim block: dims [sub*4, sub*4+4)
  const int e1 = ptr[w];                  // end (cursor after scatter)
  const int e0 = (w > 0) ? ptr[w - 1] : 0;
  const float4* __restrict__ Z4 = (const float4*)Z;

  float ax = 0.f, ay = 0.f, az = 0.f, aq = 0.f;
  for (int j = e0 + g; j < e1; j += 32) {
    int  cc[8];
    bool ok[8];
#pragma unroll
    for (int s = 0; s < 8; ++s) {
      const int js = j + 4 * s;
      ok[s] = js < e1;
      cc[s] = __builtin_nontemporal_load(ecol + (ok[s] ? js : j));
    }
    float4 xv[8];
#pragma unroll
    for (int s = 0; s < 8; ++s) xv[s] = Z4[cc[s] * 16 + sub];
#pragma unroll
    for (int s = 0; s < 8; ++s) {
      const float m = ok[s] ? 1.f : 0.f;
      ax = fmaf(m, xv[s].x, ax); ay = fmaf(m, xv[s].y, ay);
      az = fmaf(m, xv[s].z, az); aq = fmaf(m, xv[s].w, aq);
    }
  }
  // reduce across the 4 edge-slot groups
  ax += __shfl_xor(ax, 16); ax += __shfl_xor(ax, 32);
  ay += __shfl_xor(ay, 16); ay += __shfl_xor(ay, 32);
  az += __shfl_xor(az, 16); az += __shfl_xor(az, 32);
  aq += __shfl_xor(aq, 16); aq += __shfl_xor(aq, 32);

  const float dw = dis[w];
  float z0, z1, z2, z3;
  if (NOISE) {
    // ego = dw * acc; ego += sign(ego)*u*eps/||n||; Zout = dw * ego
    float v0 = dw * ax, v1 = dw * ay, v2 = dw * az, v3 = dw * aq;
    uint32_t t0 = 0u, t1 = (uint32_t)(w * EMB + sub * 4 + g);
    threefry2x32(k0, k1, t0, t1);
    const uint32_t bits = t0 ^ t1;
    const float u = __uint_as_float((bits >> 9) | 0x3f800000u) - 1.0f;
    float ss = u * u;
#pragma unroll
    for (int s = 1; s < 64; s <<= 1) ss += __shfl_xor(ss, s);
    const float inv = 1.0f / fmaxf(sqrtf(ss), 1e-12f);
    const float u0 = __shfl(u, sub);
    const float u1 = __shfl(u, 16 + sub);
    const float u2 = __shfl(u, 32 + sub);
    const float u3 = __shfl(u, 48 + sub);
    const float e = EPS_F * inv;
    v0 = fmaf(((v0 > 0.f) ? 1.f : ((v0 < 0.f) ? -1.f : 0.f)) * u0, e, v0);
    v1 = fmaf(((v1 > 0.f) ? 1.f : ((v1 < 0.f) ? -1.f : 0.f)) * u1, e, v1);
    v2 = fmaf(((v2 > 0.f) ? 1.f : ((v2 < 0.f) ? -1.f : 0.f)) * u2, e, v2);
    v3 = fmaf(((v3 > 0.f) ? 1.f : ((v3 < 0.f) ? -1.f : 0.f)) * u3, e, v3);
    z0 = dw * v0; z1 = dw * v1; z2 = dw * v2; z3 = dw * v3;
  } else {
    const float d2 = dw * dw;
    z0 = d2 * ax; z1 = d2 * ay; z2 = d2 * az; z3 = d2 * aq;
  }
  if (g == 0) {
    float4 r; r.x = z0; r.y = z1; r.z = z2; r.w = z3;
    ((float4*)Zout)[w * 16 + sub] = r;
  }
}

// Final noisy layer (k=2): its output is ONLY consumed by the batch-row
// mean-gather -> compute just the 2*BATCH rows, fuse noise + mean-accumulate.
// One wave per batch index; same gather-sum structure and same per-NODE PRNG
// indexing as k_spmm<1>, so noise is bit-identical.
__global__ __launch_bounds__(256) void k_spmm_last(const int* __restrict__ ptr,
                                                   const int* __restrict__ ecol,
                                                   const float* __restrict__ dis,
                                                   const float* __restrict__ Z,
                                                   const int* __restrict__ users,
                                                   const int* __restrict__ items,
                                                   float* __restrict__ out_u,
                                                   float* __restrict__ out_i,
                                                   uint32_t k0, uint32_t k1) {
  const int b = (blockIdx.x * blockDim.x + threadIdx.x) >> 6;
  const int lane = threadIdx.x & 63;
  if (b >= 2 * BATCH) return;
  const int g   = lane >> 4;
  const int sub = lane & 15;
  int w; float* dst;
  if (b < BATCH) { w = users[b];                     dst = out_u + (size_t)b * EMB; }
  else           { w = USER_COUNT + items[b - BATCH]; dst = out_i + (size_t)(b - BATCH) * EMB; }
  const int e1 = ptr[w];
  const int e0 = (w > 0) ? ptr[w - 1] : 0;
  const float4* __restrict__ Z4 = (const float4*)Z;

  float ax = 0.f, ay = 0.f, az = 0.f, aq = 0.f;
  for (int j = e0 + g; j < e1; j += 32) {
    int  cc[8];
    bool ok[8];
#pragma unroll
    for (int s = 0; s < 8; ++s) {
      const int js = j + 4 * s;
      ok[s] = js < e1;
      cc[s] = __builtin_nontemporal_load(ecol + (ok[s] ? js : j));
    }
    float4 xv[8];
#pragma unroll
    for (int s = 0; s < 8; ++s) xv[s] = Z4[cc[s] * 16 + sub];
#pragma unroll
    for (int s = 0; s < 8; ++s) {
      const float m = ok[s] ? 1.f : 0.f;
      ax = fmaf(m, xv[s].x, ax); ay = fmaf(m, xv[s].y, ay);
      az = fmaf(m, xv[s].z, az); aq = fmaf(m, xv[s].w, aq);
    }
  }
  ax += __shfl_xor(ax, 16); ax += __shfl_xor(ax, 32);
  ay += __shfl_xor(ay, 16); ay += __shfl_xor(ay, 32);
  az += __shfl_xor(az, 16); az += __shfl_xor(az, 32);
  aq += __shfl_xor(aq, 16); aq += __shfl_xor(aq, 32);

  const float dw = dis[w];
  float v0 = dw * ax, v1 = dw * ay, v2 = dw * az, v3 = dw * aq;
  uint32_t t0 = 0u, t1 = (uint32_t)(w * EMB + sub * 4 + g);
  threefry2x32(k0, k1, t0, t1);
  const uint32_t bits = t0 ^ t1;
  const float u = __uint_as_float((bits >> 9) | 0x3f800000u) - 1.0f;
  float ss = u * u;
#pragma unroll
  for (int s = 1; s < 64; s <<= 1) ss += __shfl_xor(ss, s);
  const float inv = 1.0f / fmaxf(sqrtf(ss), 1e-12f);
  const float u0 = __shfl(u, sub);
  const float u1 = __shfl(u, 16 + sub);
  const float u2 = __shfl(u, 32 + sub);
  const float u3 = __shfl(u, 48 + sub);
  const float e = EPS_F * inv;
  v0 = fmaf(((v0 > 0.f) ? 1.f : ((v0 < 0.f) ? -1.f : 0.f)) * u0, e, v0);
  v1 = fmaf(((v1 > 0.f) ? 1.f : ((v1 < 0.f) ? -1.f : 0.f)) * u1, e, v1);
  v2 = fmaf(((v2 > 0.f) ? 1.f : ((v2 < 0.f) ? -1.f : 0.f)) * u2, e, v2);
  v3 = fmaf(((v3 > 0.f) ? 1.f : ((v3 < 0.f) ? -1.f : 0.f)) * u3, e, v3);

  if (g == 0) {
    float4 o = ((float4*)dst)[sub];
    o.x += v0 * (1.0f / 3.0f); o.y += v1 * (1.0f / 3.0f);
    o.z += v2 * (1.0f / 3.0f); o.w += v3 * (1.0f / 3.0f);
    ((float4*)dst)[sub] = o;
  }
}

// gather batch rows from Z, recovering ego = Z * sqrt(max(deg,1));
// optional second (cl) destination at scale 1
__global__ __launch_bounds__(256) void k_gather(const float* __restrict__ Z,
                                                const int* __restrict__ deg,
                                                const int* __restrict__ users,
                                                const int* __restrict__ items,
                                                float* __restrict__ out_u,
                                                float* __restrict__ out_i,
                                                float* __restrict__ cl_u,
                                                float* __restrict__ cl_i,
                                                float scale, int init) {
  const int w = (blockIdx.x * blockDim.x + threadIdx.x) >> 6;
  const int lane = threadIdx.x & 63;
  if (w >= 2 * BATCH) return;
  int src; float* dst; float* dst2;
  if (w < BATCH) {
    src = users[w];               dst = out_u + w * EMB;
    dst2 = cl_u ? cl_u + w * EMB : nullptr;
  } else {
    int q = w - BATCH;
    src = USER_COUNT + items[q];  dst = out_i + q * EMB;
    dst2 = cl_i ? cl_i + q * EMB : nullptr;
  }
  const int d = deg[src];
  const float rdis = sqrtf((float)(d > 0 ? d : 1));
  float raw = Z[(size_t)src * EMB + lane] * rdis;
  float v = raw * scale;
  dst[lane] = init ? v : (dst[lane] + v);
  if (dst2) dst2[lane] = raw;
}

extern "C" void kernel_launch(void* const* d_in, const int* in_sizes, int n_in,
                              void* d_out, int out_size, void* d_ws, size_t ws_size,
                              hipStream_t stream) {
  const float* user_emb = (const float*)d_in[0];
  const float* item_emb = (const float*)d_in[1];
  // d_in[2] = vals: unused, recomputed bit-identically from degrees
  const int* rows  = (const int*)d_in[3];
  const int* cols  = (const int*)d_in[4];
  const int* users = (const int*)d_in[5];
  const int* items = (const int*)d_in[6];

  float* X   = (float*)d_ws;                       // 9.6M f32 (Z ping)
  float* Y   = X + (size_t)N_NODES * EMB;          // 9.6M f32 (Z pong)
  int*   deg = (int*)(Y + (size_t)N_NODES * EMB);  // 150k
  int*   ptr = deg + N_NODES;                      // 150k
  float* dis = (float*)(ptr + N_NODES);            // 150k
  int*   ecol = (int*)(dis + N_NODES);             // 4M
  int*   bsum = ecol + N_EDGES;                    // 586

  float* out  = (float*)d_out;
  float* u_all = out;
  float* i_all = out + (size_t)BATCH * EMB;
  float* u_tr  = out + (size_t)2 * BATCH * EMB;
  float* i_tr  = out + (size_t)3 * BATCH * EMB;
  float* u_cl  = out + (size_t)4 * BATCH * EMB;
  float* i_cl  = out + (size_t)5 * BATCH * EMB;

  // ---- build CSR (per launch, deterministic work) ----
  hipMemsetAsync(deg, 0, sizeof(int) * N_NODES, stream);
  k_hist<<<1024, 256, 0, stream>>>(rows, cols, deg);
  k_bsum<<<NB_SCAN, 256, 0, stream>>>(deg, bsum);
  k_bscan<<<1, 64, 0, stream>>>(bsum, NB_SCAN);
  k_finalize<<<NB_SCAN, 256, 0, stream>>>(deg, bsum, ptr, dis);
  k_scatter<<<2048, 256, 0, stream>>>(rows, cols, ptr, ecol);

  // ---- Z0 = dis * concat(user_emb, item_emb) ----
  k_init<<<(N_NODES * 16 + 255) / 256, 256, 0, stream>>>(user_emb, item_emb, dis, X);

  const int spmm_grid = (N_NODES * EMB + 255) / 256; // 37500
  const int gat_grid  = (2 * BATCH * EMB + 255) / 256; // 2048

  // ---- phase 1: 3 clean layers, mean-gather into outputs 0,1 ----
  for (int l = 0; l < 3; ++l) {
    k_spmm<0><<<spmm_grid, 256, 0, stream>>>(ptr, ecol, dis, X, Y, 0u, 0u);
    k_gather<<<gat_grid, 256, 0, stream>>>(Y, deg, users, items, u_all, i_all,
                                           nullptr, nullptr, 1.0f / 3.0f, l == 0);
    float* t = X; X = Y; Y = t;
  }

  // ---- phase 2: noisy layers k=0,1 full-width; k=2 batch-rows-only fused ----
  for (int k = 0; k < 2; ++k) {
    uint32_t f0 = 0u, f1 = (uint32_t)k;      // fold_in(key(42), k)
    threefry2x32(0u, 42u, f0, f1);
    k_spmm<1><<<spmm_grid, 256, 0, stream>>>(ptr, ecol, dis, X, Y, f0, f1);
    k_gather<<<gat_grid, 256, 0, stream>>>(Y, deg, users, items, u_tr, i_tr,
                                           (k == 0) ? u_cl : nullptr,
                                           (k == 0) ? i_cl : nullptr,
                                           1.0f / 3.0f, k == 0);
    float* t = X; X = Y; Y = t;
  }
  {
    uint32_t f0 = 0u, f1 = 2u;               // fold_in(key(42), 2)
    threefry2x32(0u, 42u, f0, f1);
    k_spmm_last<<<gat_grid, 256, 0, stream>>>(ptr, ecol, dis, X, users, items,
                                              u_tr, i_tr, f0, f1);
  }
}

// Round 13
// 987.381 us; speedup vs baseline: 2.8310x; 1.0038x over previous
//
#include <hip/hip_runtime.h>
#include <stdint.h>

#define USER_COUNT 100000
#define ITEM_COUNT 50000
#define N_NODES    150000
#define EMB        64
#define N_EDGES    4000000
#define BATCH      4096
#define EPS_F      0.2f
#define NB_SCAN    ((N_NODES + 255) / 256)   // 586

// ---- bucket geometry: degree-balanced (users deg~20 get 1024 nodes,
// items deg~40 get 512 nodes -> ~20K edges per bucket uniformly) ----
#define UBKN 98                  // ceil(100000/1024)
#define IBKN 98                  // ceil(50000/512)
#define NBK  (UBKN + IBKN)       // 196
#define FIFO_CAP 32
#define NBLK1 256
#define CHUNK ((N_EDGES / 2 + NBLK1 - 1) / NBLK1)  // 7813
#define BIN_CAP 24576            // 96KB LDS image; max bucket ~21K edges

typedef int int4v __attribute__((ext_vector_type(4)));

__device__ inline int bucket_of(int n) {
  return (n < USER_COUNT) ? (n >> 10) : (UBKN + ((n - USER_COUNT) >> 9));
}
__device__ inline int bucket_lo(int b) {
  return (b < UBKN) ? (b << 10) : (USER_COUNT + ((b - UBKN) << 9));
}
__device__ inline int bucket_hi(int b) {
  int hi = (b < UBKN) ? ((b + 1) << 10) : (USER_COUNT + ((b - UBKN + 1) << 9));
  int cap = (b < UBKN) ? USER_COUNT : N_NODES;
  return hi < cap ? hi : cap;
}

// ---- JAX threefry-2x32 (20 rounds), bit-exact ----
__host__ __device__ inline void threefry2x32(uint32_t k0, uint32_t k1,
                                             uint32_t& x0, uint32_t& x1) {
  const uint32_t ks2 = k0 ^ k1 ^ 0x1BD11BDAu;
  x0 += k0; x1 += k1;
#define TF_ROT(r) { x0 += x1; x1 = (x1 << (r)) | (x1 >> (32 - (r))); x1 ^= x0; }
  TF_ROT(13) TF_ROT(15) TF_ROT(26) TF_ROT(6)
  x0 += k1;  x1 += ks2 + 1u;
  TF_ROT(17) TF_ROT(29) TF_ROT(16) TF_ROT(24)
  x0 += ks2; x1 += k0 + 2u;
  TF_ROT(13) TF_ROT(15) TF_ROT(26) TF_ROT(6)
  x0 += k0;  x1 += k1 + 3u;
  TF_ROT(17) TF_ROT(29) TF_ROT(16) TF_ROT(24)
  x0 += k1;  x1 += ks2 + 4u;
  TF_ROT(13) TF_ROT(15) TF_ROT(26) TF_ROT(6)
  x0 += ks2; x1 += k0 + 5u;
#undef TF_ROT
}

// mirror structure: edges [2M,4M) are edges [0,2M) swapped -> one pass,
// two atomics per edge. Same histogram as the full stream.
__global__ void k_hist(const int* __restrict__ rows, const int* __restrict__ cols,
                       int* __restrict__ deg) {
  const int4v* __restrict__ r4 = (const int4v*)rows;
  const int4v* __restrict__ c4 = (const int4v*)cols;
  int stride = gridDim.x * blockDim.x;
  for (int e = blockIdx.x * blockDim.x + threadIdx.x; e < N_EDGES / 8; e += stride) {
    int4v r = __builtin_nontemporal_load(r4 + e);
    int4v c = __builtin_nontemporal_load(c4 + e);
    atomicAdd(&deg[r.x], 1); atomicAdd(&deg[r.y], 1);
    atomicAdd(&deg[r.z], 1); atomicAdd(&deg[r.w], 1);
    atomicAdd(&deg[c.x], 1); atomicAdd(&deg[c.y], 1);
    atomicAdd(&deg[c.z], 1); atomicAdd(&deg[c.w], 1);
  }
}

// ---- parallel scan over deg -> INCLUSIVE prefix in ptr (ptr[i] = end of row i) ----
__global__ void k_bsum(const int* __restrict__ deg, int* __restrict__ bsum) {
  const int i = blockIdx.x * 256 + threadIdx.x;
  const int lane = threadIdx.x & 63, wid = threadIdx.x >> 6;
  int d = (i < N_NODES) ? deg[i] : 0;
#pragma unroll
  for (int s = 32; s; s >>= 1) d += __shfl_down(d, s);
  __shared__ int ws[4];
  if (lane == 0) ws[wid] = d;
  __syncthreads();
  if (threadIdx.x == 0) bsum[blockIdx.x] = ws[0] + ws[1] + ws[2] + ws[3];
}

__global__ void k_bscan(int* __restrict__ bsum, int nb) { // in-place -> exclusive
  const int lane = threadIdx.x; // blockDim = 64
  int carry = 0;
  for (int base = 0; base < nb; base += 64) {
    const int idx = base + lane;
    int v = (idx < nb) ? bsum[idx] : 0;
    int inc = v;
#pragma unroll
    for (int s = 1; s < 64; s <<= 1) { int t = __shfl_up(inc, s); if (lane >= s) inc += t; }
    if (idx < nb) bsum[idx] = inc - v + carry;
    carry += __shfl(inc, 63);
  }
}

__global__ void k_finalize(const int* __restrict__ deg, const int* __restrict__ bsum,
                           int* __restrict__ ptr, float* __restrict__ dis) {
  const int i = blockIdx.x * 256 + threadIdx.x;
  const int lane = threadIdx.x & 63, wid = threadIdx.x >> 6;
  const int d = (i < N_NODES) ? deg[i] : 0;
  int inc = d;
#pragma unroll
  for (int s = 1; s < 64; s <<= 1) { int t = __shfl_up(inc, s); if (lane >= s) inc += t; }
  __shared__ int ws[4];
  if (lane == 63) ws[wid] = inc;
  __syncthreads();
  int woff = bsum[blockIdx.x];
  for (int w = 0; w < wid; ++w) woff += ws[w];
  if (i < N_NODES) {
    ptr[i] = woff + inc;                     // INCLUSIVE: end of row i
    dis[i] = 1.0f / sqrtf((float)(d > 0 ? d : 1));
  }
}

__global__ void k_bcur(const int* __restrict__ ptr, int* __restrict__ bcur) {
  const int b = threadIdx.x;
  if (b >= NBK) return;
  const int lo = bucket_lo(b);
  bcur[b] = (lo == 0) ? 0 : ptr[lo - 1];     // pair-region start per bucket
}

// Pass 1: stream first 2M (r,c); insert (r,c)->bkt(r) and (c,r)->bkt(c) into
// LDS ring-FIFOs; flush 16-pair (128B) contiguous runs via one global-cursor
// atomic per run. Coalesced writes beat the no-write-allocate L2 (R6/R9/R11:
// scattered 4B stores cost a full line each; teams/nt/chains never fixed it).
__global__ __launch_bounds__(256) void k_p1(const int* __restrict__ rows,
                                            const int* __restrict__ cols,
                                            int* __restrict__ bcur,
                                            int* __restrict__ pairs) {
  __shared__ int fifo[NBK * FIFO_CAP * 2];
  __shared__ int cnt[NBK], tail[NBK], rc[NBK];
  __shared__ int wlB[NBK], wlG[NBK], wlT[NBK], wlM[NBK];
  __shared__ unsigned char ovf[NBK];
  __shared__ int wlN;
  const int tid = threadIdx.x;
  for (int b = tid; b < NBK; b += 256) { cnt[b] = 0; tail[b] = 0; }
  const int eStart = blockIdx.x * CHUNK;
  const int eEnd = (eStart + CHUNK < N_EDGES / 2) ? eStart + CHUNK : N_EDGES / 2;
  for (int base = eStart; base < eEnd; base += 256) {
    const int e = base + tid;
    const bool val = e < eEnd;
    int r = 0, c = 0;
    if (val) { r = __builtin_nontemporal_load(rows + e);
               c = __builtin_nontemporal_load(cols + e); }
    for (int b = tid; b < NBK; b += 256) rc[b] = 0;
    if (tid == 0) wlN = 0;
    __syncthreads();
    if (val) { atomicAdd(&rc[bucket_of(r)], 1); atomicAdd(&rc[bucket_of(c)], 1); }
    __syncthreads();
    for (int b = tid; b < NBK; b += 256)
      ovf[b] = (cnt[b] - tail[b] + rc[b] > FIFO_CAP) ? 1 : 0;
    __syncthreads();
    if (val) {
#pragma unroll
      for (int dir = 0; dir < 2; ++dir) {
        const int a = dir ? c : r, bnode = dir ? r : c;
        const int bb = bucket_of(a);
        if (ovf[bb]) {
          int g = atomicAdd(&bcur[bb], 1);
          pairs[2 * g] = a; pairs[2 * g + 1] = bnode;   // rare spill
        } else {
          int idx = atomicAdd(&cnt[bb], 1);
          int s = idx & (FIFO_CAP - 1);
          fifo[(bb * FIFO_CAP + s) * 2]     = a;
          fifo[(bb * FIFO_CAP + s) * 2 + 1] = bnode;
        }
      }
    }
    __syncthreads();
    for (int b = tid; b < NBK; b += 256) {
      int m = (cnt[b] - tail[b]) & ~15;                 // 0,16,32
      if (m > 0) {
        int g = atomicAdd(&bcur[b], m);
        int w = atomicAdd(&wlN, 1);
        wlB[w] = b; wlG[w] = g; wlT[w] = tail[b]; wlM[w] = m;
        tail[b] += m;
      }
    }
    __syncthreads();
    const int nw = wlN;
    for (int j = tid; j < nw * FIFO_CAP; j += 256) {
      const int wi = j / FIFO_CAP, k = j % FIFO_CAP;
      if (k < wlM[wi]) {
        const int b = wlB[wi];
        const int s = (wlT[wi] + k) & (FIFO_CAP - 1);
        const int g = wlG[wi] + k;
        pairs[2 * g]     = fifo[(b * FIFO_CAP + s) * 2];
        pairs[2 * g + 1] = fifo[(b * FIFO_CAP + s) * 2 + 1];
      }
    }
    __syncthreads();
  }
  // final drain (<=31 pairs per bucket, ~64B+ runs)
  for (int b = tid; b < NBK; b += 256) {
    const int m = cnt[b] - tail[b];
    if (m > 0) {
      int g = atomicAdd(&bcur[b], m);
      for (int k = 0; k < m; ++k) {
        const int s = (tail[b] + k) & (FIFO_CAP - 1);
        pairs[2 * (g + k)]     = fifo[(b * FIFO_CAP + s) * 2];
        pairs[2 * (g + k) + 1] = fifo[(b * FIFO_CAP + s) * 2 + 1];
      }
    }
  }
}

// Pass 2: one block per bucket. Read contiguous pair region (coalesced),
// bin into LDS image of the bucket's ecol segment, write image coalesced.
__global__ __launch_bounds__(256) void k_bin(const int* __restrict__ ptr,
                                             const int* __restrict__ pairs,
                                             int* __restrict__ ecol) {
  __shared__ int img[BIN_CAP];
  __shared__ int cur[1024];
  const int b = blockIdx.x;
  const int tid = threadIdx.x;
  const int lo = bucket_lo(b), hi = bucket_hi(b);
  const int base = (lo == 0) ? 0 : ptr[lo - 1];
  const int end  = ptr[hi - 1];
  const int n = end - base;
  for (int r = lo + tid; r < hi; r += 256)
    cur[r - lo] = ((r == 0) ? 0 : ptr[r - 1]) - base;
  __syncthreads();
  const int2* __restrict__ p2 = (const int2*)pairs;
  if (n <= BIN_CAP) {
    for (int j = tid; j < n; j += 256) {
      const int2 pr = p2[base + j];
      const int p = atomicAdd(&cur[pr.x - lo], 1);
      img[p] = pr.y;
    }
    __syncthreads();
    for (int j = tid; j < n; j += 256) ecol[base + j] = img[j];
  } else { // unreachable safety fallback
    for (int j = tid; j < n; j += 256) {
      const int2 pr = p2[base + j];
      const int p = atomicAdd(&cur[pr.x - lo], 1);
      ecol[base + p] = pr.y;
    }
  }
}

// Z0 = dis * concat(user_emb, item_emb), float4-wide
__global__ __launch_bounds__(256) void k_init(const float* __restrict__ ue,
                                              const float* __restrict__ ie,
                                              const float* __restrict__ dis,
                                              float* __restrict__ Z) {
  const int idx = blockIdx.x * blockDim.x + threadIdx.x; // float4 index
  if (idx >= N_NODES * 16) return;
  float4 v = (idx < USER_COUNT * 16) ? ((const float4*)ue)[idx]
                                     : ((const float4*)ie)[idx - USER_COUNT * 16];
  const float d = dis[idx >> 4];
  v.x *= d; v.y *= d; v.z *= d; v.w *= d;
  ((float4*)Z)[idx] = v;
}

// One wave per output row, Z-iteration gather-sum; 32 gathers in flight.
// fp32 throughout (R8: narrow Z flips sign(ego) -> fails).
template <int NOISE>
__global__ __launch_bounds__(256) void k_spmm(const int* __restrict__ ptr,
                                              const int* __restrict__ ecol,
                                              const float* __restrict__ dis,
                                              const float* __restrict__ Z,
                                              float* __restrict__ Zout,
                                              uint32_t k0, uint32_t k1) {
  const int w = (blockIdx.x * blockDim.x + threadIdx.x) >> 6;
  const int lane = threadIdx.x & 63;
  if (w >= N_NODES) return;
  const int g   = lane >> 4;
  const int sub = lane & 15;
  const int e1 = ptr[w];
  const int e0 = (w > 0) ? ptr[w - 1] : 0;
  const float4* __restrict__ Z4 = (const float4*)Z;

  float ax = 0.f, ay = 0.f, az = 0.f, aq = 0.f;
  for (int j = e0 + g; j < e1; j += 32) {
    int  cc[8];
    bool ok[8];
#pragma unroll
    for (int s = 0; s < 8; ++s) {
      const int js = j + 4 * s;
      ok[s] = js < e1;
      cc[s] = __builtin_nontemporal_load(ecol + (ok[s] ? js : j));
    }
    float4 xv[8];
#pragma unroll
    for (int s = 0; s < 8; ++s) xv[s] = Z4[cc[s] * 16 + sub];
#pragma unroll
    for (int s = 0; s < 8; ++s) {
      const float m = ok[s] ? 1.f : 0.f;
      ax = fmaf(m, xv[s].x, ax); ay = fmaf(m, xv[s].y, ay);
      az = fmaf(m, xv[s].z, az); aq = fmaf(m, xv[s].w, aq);
    }
  }
  ax += __shfl_xor(ax, 16); ax += __shfl_xor(ax, 32);
  ay += __shfl_xor(ay, 16); ay += __shfl_xor(ay, 32);
  az += __shfl_xor(az, 16); az += __shfl_xor(az, 32);
  aq += __shfl_xor(aq, 16); aq += __shfl_xor(aq, 32);

  const float dw = dis[w];
  float z0, z1, z2, z3;
  if (NOISE) {
    float v0 = dw * ax, v1 = dw * ay, v2 = dw * az, v3 = dw * aq;
    uint32_t t0 = 0u, t1 = (uint32_t)(w * EMB + sub * 4 + g);
    threefry2x32(k0, k1, t0, t1);
    const uint32_t bits = t0 ^ t1;
    const float u = __uint_as_float((bits >> 9) | 0x3f800000u) - 1.0f;
    float ss = u * u;
#pragma unroll
    for (int s = 1; s < 64; s <<= 1) ss += __shfl_xor(ss, s);
    const float inv = 1.0f / fmaxf(sqrtf(ss), 1e-12f);
    const float u0 = __shfl(u, sub);
    const float u1 = __shfl(u, 16 + sub);
    const float u2 = __shfl(u, 32 + sub);
    const float u3 = __shfl(u, 48 + sub);
    const float e = EPS_F * inv;
    v0 = fmaf(((v0 > 0.f) ? 1.f : ((v0 < 0.f) ? -1.f : 0.f)) * u0, e, v0);
    v1 = fmaf(((v1 > 0.f) ? 1.f : ((v1 < 0.f) ? -1.f : 0.f)) * u1, e, v1);
    v2 = fmaf(((v2 > 0.f) ? 1.f : ((v2 < 0.f) ? -1.f : 0.f)) * u2, e, v2);
    v3 = fmaf(((v3 > 0.f) ? 1.f : ((v3 < 0.f) ? -1.f : 0.f)) * u3, e, v3);
    z0 = dw * v0; z1 = dw * v1; z2 = dw * v2; z3 = dw * v3;
  } else {
    const float d2 = dw * dw;
    z0 = d2 * ax; z1 = d2 * ay; z2 = d2 * az; z3 = d2 * aq;
  }
  if (g == 0) {
    float4 r; r.x = z0; r.y = z1; r.z = z2; r.w = z3;
    ((float4*)Zout)[w * 16 + sub] = r;
  }
}

// Final noisy layer (k=2): only batch rows needed -> fused spmm+noise+mean.
__global__ __launch_bounds__(256) void k_spmm_last(const int* __restrict__ ptr,
                                                   const int* __restrict__ ecol,
                                                   const float* __restrict__ dis,
                                                   const float* __restrict__ Z,
                                                   const int* __restrict__ users,
                                                   const int* __restrict__ items,
                                                   float* __restrict__ out_u,
                                                   float* __restrict__ out_i,
                                                   uint32_t k0, uint32_t k1) {
  const int b = (blockIdx.x * blockDim.x + threadIdx.x) >> 6;
  const int lane = threadIdx.x & 63;
  if (b >= 2 * BATCH) return;
  const int g   = lane >> 4;
  const int sub = lane & 15;
  int w; float* dst;
  if (b < BATCH) { w = users[b];                      dst = out_u + (size_t)b * EMB; }
  else           { w = USER_COUNT + items[b - BATCH]; dst = out_i + (size_t)(b - BATCH) * EMB; }
  const int e1 = ptr[w];
  const int e0 = (w > 0) ? ptr[w - 1] : 0;
  const float4* __restrict__ Z4 = (const float4*)Z;

  float ax = 0.f, ay = 0.f, az = 0.f, aq = 0.f;
  for (int j = e0 + g; j < e1; j += 32) {
    int  cc[8];
    bool ok[8];
#pragma unroll
    for (int s = 0; s < 8; ++s) {
      const int js = j + 4 * s;
      ok[s] = js < e1;
      cc[s] = __builtin_nontemporal_load(ecol + (ok[s] ? js : j));
    }
    float4 xv[8];
#pragma unroll
    for (int s = 0; s < 8; ++s) xv[s] = Z4[cc[s] * 16 + sub];
#pragma unroll
    for (int s = 0; s < 8; ++s) {
      const float m = ok[s] ? 1.f : 0.f;
      ax = fmaf(m, xv[s].x, ax); ay = fmaf(m, xv[s].y, ay);
      az = fmaf(m, xv[s].z, az); aq = fmaf(m, xv[s].w, aq);
    }
  }
  ax += __shfl_xor(ax, 16); ax += __shfl_xor(ax, 32);
  ay += __shfl_xor(ay, 16); ay += __shfl_xor(ay, 32);
  az += __shfl_xor(az, 16); az += __shfl_xor(az, 32);
  aq += __shfl_xor(aq, 16); aq += __shfl_xor(aq, 32);

  const float dw = dis[w];
  float v0 = dw * ax, v1 = dw * ay, v2 = dw * az, v3 = dw * aq;
  uint32_t t0 = 0u, t1 = (uint32_t)(w * EMB + sub * 4 + g);
  threefry2x32(k0, k1, t0, t1);
  const uint32_t bits = t0 ^ t1;
  const float u = __uint_as_float((bits >> 9) | 0x3f800000u) - 1.0f;
  float ss = u * u;
#pragma unroll
  for (int s = 1; s < 64; s <<= 1) ss += __shfl_xor(ss, s);
  const float inv = 1.0f / fmaxf(sqrtf(ss), 1e-12f);
  const float u0 = __shfl(u, sub);
  const float u1 = __shfl(u, 16 + sub);
  const float u2 = __shfl(u, 32 + sub);
  const float u3 = __shfl(u, 48 + sub);
  const float e = EPS_F * inv;
  v0 = fmaf(((v0 > 0.f) ? 1.f : ((v0 < 0.f) ? -1.f : 0.f)) * u0, e, v0);
  v1 = fmaf(((v1 > 0.f) ? 1.f : ((v1 < 0.f) ? -1.f : 0.f)) * u1, e, v1);
  v2 = fmaf(((v2 > 0.f) ? 1.f : ((v2 < 0.f) ? -1.f : 0.f)) * u2, e, v2);
  v3 = fmaf(((v3 > 0.f) ? 1.f : ((v3 < 0.f) ? -1.f : 0.f)) * u3, e, v3);

  if (g == 0) {
    float4 o = ((float4*)dst)[sub];
    o.x += v0 * (1.0f / 3.0f); o.y += v1 * (1.0f / 3.0f);
    o.z += v2 * (1.0f / 3.0f); o.w += v3 * (1.0f / 3.0f);
    ((float4*)dst)[sub] = o;
  }
}

// gather batch rows from Z, recovering ego = Z * sqrt(max(deg,1))
__global__ __launch_bounds__(256) void k_gather(const float* __restrict__ Z,
                                                const int* __restrict__ deg,
                                                const int* __restrict__ users,
                                                const int* __restrict__ items,
                                                float* __restrict__ out_u,
                                                float* __restrict__ out_i,
                                                float* __restrict__ cl_u,
                                                float* __restrict__ cl_i,
                                                float scale, int init) {
  const int w = (blockIdx.x * blockDim.x + threadIdx.x) >> 6;
  const int lane = threadIdx.x & 63;
  if (w >= 2 * BATCH) return;
  int src; float* dst; float* dst2;
  if (w < BATCH) {
    src = users[w];               dst = out_u + w * EMB;
    dst2 = cl_u ? cl_u + w * EMB : nullptr;
  } else {
    int q = w - BATCH;
    src = USER_COUNT + items[q];  dst = out_i + q * EMB;
    dst2 = cl_i ? cl_i + q * EMB : nullptr;
  }
  const int d = deg[src];
  const float rdis = sqrtf((float)(d > 0 ? d : 1));
  float raw = Z[(size_t)src * EMB + lane] * rdis;
  float v = raw * scale;
  dst[lane] = init ? v : (dst[lane] + v);
  if (dst2) dst2[lane] = raw;
}

extern "C" void kernel_launch(void* const* d_in, const int* in_sizes, int n_in,
                              void* d_out, int out_size, void* d_ws, size_t ws_size,
                              hipStream_t stream) {
  const float* user_emb = (const float*)d_in[0];
  const float* item_emb = (const float*)d_in[1];
  // d_in[2] = vals: unused, recomputed bit-identically from degrees
  const int* rows  = (const int*)d_in[3];
  const int* cols  = (const int*)d_in[4];
  const int* users = (const int*)d_in[5];
  const int* items = (const int*)d_in[6];

  float* X   = (float*)d_ws;                       // 9.6M f32 (Z ping)
  float* Y   = X + (size_t)N_NODES * EMB;          // 9.6M f32 (Z pong)
  int*   deg = (int*)(Y + (size_t)N_NODES * EMB);  // 150k
  int*   ptr = deg + N_NODES;                      // 150k
  float* dis = (float*)(ptr + N_NODES);            // 150k
  int*   ecol = (int*)(dis + N_NODES);             // 4M
  int*   bsum = ecol + N_EDGES;                    // 586
  int*   bcur = bsum + 1024;                       // 196
  int*   pairs = (int*)Y;                          // 8M ints, aliases Y (dead
                                                   // until first spmm output)

  float* out  = (float*)d_out;
  float* u_all = out;
  float* i_all = out + (size_t)BATCH * EMB;
  float* u_tr  = out + (size_t)2 * BATCH * EMB;
  float* i_tr  = out + (size_t)3 * BATCH * EMB;
  float* u_cl  = out + (size_t)4 * BATCH * EMB;
  float* i_cl  = out + (size_t)5 * BATCH * EMB;

  // ---- build CSR via 2-pass LDS-staged counting sort ----
  hipMemsetAsync(deg, 0, sizeof(int) * N_NODES, stream);
  k_hist<<<1024, 256, 0, stream>>>(rows, cols, deg);
  k_bsum<<<NB_SCAN, 256, 0, stream>>>(deg, bsum);
  k_bscan<<<1, 64, 0, stream>>>(bsum, NB_SCAN);
  k_finalize<<<NB_SCAN, 256, 0, stream>>>(deg, bsum, ptr, dis);
  k_bcur<<<1, 256, 0, stream>>>(ptr, bcur);
  k_p1<<<NBLK1, 256, 0, stream>>>(rows, cols, bcur, pairs);
  k_bin<<<NBK, 256, 0, stream>>>(ptr, pairs, ecol);

  // ---- Z0 = dis * concat(user_emb, item_emb) ----
  k_init<<<(N_NODES * 16 + 255) / 256, 256, 0, stream>>>(user_emb, item_emb, dis, X);

  const int spmm_grid = (N_NODES * EMB + 255) / 256; // 37500
  const int gat_grid  = (2 * BATCH * EMB + 255) / 256; // 2048

  // ---- phase 1: 3 clean layers, mean-gather into outputs 0,1 ----
  for (int l = 0; l < 3; ++l) {
    k_spmm<0><<<spmm_grid, 256, 0, stream>>>(ptr, ecol, dis, X, Y, 0u, 0u);
    k_gather<<<gat_grid, 256, 0, stream>>>(Y, deg, users, items, u_all, i_all,
                                           nullptr, nullptr, 1.0f / 3.0f, l == 0);
    float* t = X; X = Y; Y = t;
  }

  // ---- phase 2: noisy layers k=0,1 full-width; k=2 batch-rows-only fused ----
  for (int k = 0; k < 2; ++k) {
    uint32_t f0 = 0u, f1 = (uint32_t)k;      // fold_in(key(42), k)
    threefry2x32(0u, 42u, f0, f1);
    k_spmm<1><<<spmm_grid, 256, 0, stream>>>(ptr, ecol, dis, X, Y, f0, f1);
    k_gather<<<gat_grid, 256, 0, stream>>>(Y, deg, users, items, u_tr, i_tr,
                                           (k == 0) ? u_cl : nullptr,
                                           (k == 0) ? i_cl : nullptr,
                                           1.0f / 3.0f, k == 0);
    float* t = X; X = Y; Y = t;
  }
  {
    uint32_t f0 = 0u, f1 = 2u;               // fold_in(key(42), 2)
    threefry2x32(0u, 42u, f0, f1);
    k_spmm_last<<<gat_grid, 256, 0, stream>>>(ptr, ecol, dis, X, users, items,
                                              u_tr, i_tr, f0, f1);
  }
}

// Round 14
// 864.834 us; speedup vs baseline: 3.2322x; 1.1417x over previous
//
#include <hip/hip_runtime.h>
#include <stdint.h>

#define USER_COUNT 100000
#define ITEM_COUNT 50000
#define N_NODES    150000
#define EMB        64
#define N_EDGES    4000000
#define BATCH      4096
#define EPS_F      0.2f

// ---- bucket geometry: degree-balanced (users deg~20 get 1024 nodes,
// items deg~40 get 512 nodes -> ~20K edges per bucket uniformly) ----
#define UBKN 98                  // ceil(100000/1024)
#define IBKN 98                  // ceil(50000/512)
#define NBK  (UBKN + IBKN)       // 196
#define FIFO_CAP 32
#define NBLK1 256
#define CHUNK ((N_EDGES / 2 + NBLK1 - 1) / NBLK1)  // 7813
#define BIN_CAP 24576            // 96KB LDS image; max bucket ~21K edges

typedef int int4v __attribute__((ext_vector_type(4)));

__device__ inline int bucket_of(int n) {
  return (n < USER_COUNT) ? (n >> 10) : (UBKN + ((n - USER_COUNT) >> 9));
}
__device__ inline int bucket_lo(int b) {
  return (b < UBKN) ? (b << 10) : (USER_COUNT + ((b - UBKN) << 9));
}
__device__ inline int bucket_hi(int b) {
  int hi = (b < UBKN) ? ((b + 1) << 10) : (USER_COUNT + ((b - UBKN + 1) << 9));
  int cap = (b < UBKN) ? USER_COUNT : N_NODES;
  return hi < cap ? hi : cap;
}

// ---- JAX threefry-2x32 (20 rounds), bit-exact ----
__host__ __device__ inline void threefry2x32(uint32_t k0, uint32_t k1,
                                             uint32_t& x0, uint32_t& x1) {
  const uint32_t ks2 = k0 ^ k1 ^ 0x1BD11BDAu;
  x0 += k0; x1 += k1;
#define TF_ROT(r) { x0 += x1; x1 = (x1 << (r)) | (x1 >> (32 - (r))); x1 ^= x0; }
  TF_ROT(13) TF_ROT(15) TF_ROT(26) TF_ROT(6)
  x0 += k1;  x1 += ks2 + 1u;
  TF_ROT(17) TF_ROT(29) TF_ROT(16) TF_ROT(24)
  x0 += ks2; x1 += k0 + 2u;
  TF_ROT(13) TF_ROT(15) TF_ROT(26) TF_ROT(6)
  x0 += k0;  x1 += k1 + 3u;
  TF_ROT(17) TF_ROT(29) TF_ROT(16) TF_ROT(24)
  x0 += k1;  x1 += ks2 + 4u;
  TF_ROT(13) TF_ROT(15) TF_ROT(26) TF_ROT(6)
  x0 += ks2; x1 += k0 + 5u;
#undef TF_ROT
}

// Bucket histogram: 196 LDS bins per block, one global atomic per bin per
// block (~50K total). Replaces the 8M-global-atomic node histogram (R13:
// 160us, 124MB coherence write traffic -> LDS-local, ~1MB).
__global__ __launch_bounds__(256) void k_bkhist(const int* __restrict__ rows,
                                                const int* __restrict__ cols,
                                                int* __restrict__ bkcnt) {
  __shared__ int h[NBK];
  for (int i = threadIdx.x; i < NBK; i += 256) h[i] = 0;
  __syncthreads();
  const int stride = gridDim.x * blockDim.x;
  for (int e = blockIdx.x * blockDim.x + threadIdx.x; e < N_EDGES / 2; e += stride) {
    const int r = __builtin_nontemporal_load(rows + e);
    const int c = __builtin_nontemporal_load(cols + e);
    atomicAdd(&h[bucket_of(r)], 1);
    atomicAdd(&h[bucket_of(c)], 1);
  }
  __syncthreads();
  for (int i = threadIdx.x; i < NBK; i += 256)
    if (h[i]) atomicAdd(&bkcnt[i], h[i]);
}

// 1-wave exclusive scan of bucket counts -> bstart[0..NBK] and bcur init.
__global__ void k_bkscan(const int* __restrict__ bkcnt, int* __restrict__ bstart,
                         int* __restrict__ bcur) {
  const int lane = threadIdx.x; // blockDim = 64
  int carry = 0;
  for (int base = 0; base < NBK; base += 64) {
    const int idx = base + lane;
    int v = (idx < NBK) ? bkcnt[idx] : 0;
    int inc = v;
#pragma unroll
    for (int s = 1; s < 64; s <<= 1) { int t = __shfl_up(inc, s); if (lane >= s) inc += t; }
    if (idx < NBK) { bstart[idx] = inc - v + carry; bcur[idx] = inc - v + carry; }
    carry += __shfl(inc, 63);
  }
  if (lane == 0) bstart[NBK] = carry;   // == N_EDGES
}

// Pass 1: stream first 2M (r,c); insert (r,c)->bkt(r) and (c,r)->bkt(c) into
// LDS ring-FIFOs; flush 16-pair (128B) contiguous runs via one global-cursor
// atomic per run. Coalesced writes beat the no-write-allocate L2.
__global__ __launch_bounds__(256) void k_p1(const int* __restrict__ rows,
                                            const int* __restrict__ cols,
                                            int* __restrict__ bcur,
                                            int* __restrict__ pairs) {
  __shared__ int fifo[NBK * FIFO_CAP * 2];
  __shared__ int cnt[NBK], tail[NBK], rc[NBK];
  __shared__ int wlB[NBK], wlG[NBK], wlT[NBK], wlM[NBK];
  __shared__ unsigned char ovf[NBK];
  __shared__ int wlN;
  const int tid = threadIdx.x;
  for (int b = tid; b < NBK; b += 256) { cnt[b] = 0; tail[b] = 0; }
  const int eStart = blockIdx.x * CHUNK;
  const int eEnd = (eStart + CHUNK < N_EDGES / 2) ? eStart + CHUNK : N_EDGES / 2;
  for (int base = eStart; base < eEnd; base += 256) {
    const int e = base + tid;
    const bool val = e < eEnd;
    int r = 0, c = 0;
    if (val) { r = __builtin_nontemporal_load(rows + e);
               c = __builtin_nontemporal_load(cols + e); }
    for (int b = tid; b < NBK; b += 256) rc[b] = 0;
    if (tid == 0) wlN = 0;
    __syncthreads();
    if (val) { atomicAdd(&rc[bucket_of(r)], 1); atomicAdd(&rc[bucket_of(c)], 1); }
    __syncthreads();
    for (int b = tid; b < NBK; b += 256)
      ovf[b] = (cnt[b] - tail[b] + rc[b] > FIFO_CAP) ? 1 : 0;
    __syncthreads();
    if (val) {
#pragma unroll
      for (int dir = 0; dir < 2; ++dir) {
        const int a = dir ? c : r, bnode = dir ? r : c;
        const int bb = bucket_of(a);
        if (ovf[bb]) {
          int g = atomicAdd(&bcur[bb], 1);
          pairs[2 * g] = a; pairs[2 * g + 1] = bnode;   // rare spill
        } else {
          int idx = atomicAdd(&cnt[bb], 1);
          int s = idx & (FIFO_CAP - 1);
          fifo[(bb * FIFO_CAP + s) * 2]     = a;
          fifo[(bb * FIFO_CAP + s) * 2 + 1] = bnode;
        }
      }
    }
    __syncthreads();
    for (int b = tid; b < NBK; b += 256) {
      int m = (cnt[b] - tail[b]) & ~15;                 // 0,16,32
      if (m > 0) {
        int g = atomicAdd(&bcur[b], m);
        int w = atomicAdd(&wlN, 1);
        wlB[w] = b; wlG[w] = g; wlT[w] = tail[b]; wlM[w] = m;
        tail[b] += m;
      }
    }
    __syncthreads();
    const int nw = wlN;
    for (int j = tid; j < nw * FIFO_CAP; j += 256) {
      const int wi = j / FIFO_CAP, k = j % FIFO_CAP;
      if (k < wlM[wi]) {
        const int b = wlB[wi];
        const int s = (wlT[wi] + k) & (FIFO_CAP - 1);
        const int g = wlG[wi] + k;
        pairs[2 * g]     = fifo[(b * FIFO_CAP + s) * 2];
        pairs[2 * g + 1] = fifo[(b * FIFO_CAP + s) * 2 + 1];
      }
    }
    __syncthreads();
  }
  // final drain (<=31 pairs per bucket)
  for (int b = tid; b < NBK; b += 256) {
    const int m = cnt[b] - tail[b];
    if (m > 0) {
      int g = atomicAdd(&bcur[b], m);
      for (int k = 0; k < m; ++k) {
        const int s = (tail[b] + k) & (FIFO_CAP - 1);
        pairs[2 * (g + k)]     = fifo[(b * FIFO_CAP + s) * 2];
        pairs[2 * (g + k) + 1] = fifo[(b * FIFO_CAP + s) * 2 + 1];
      }
    }
  }
}

// Pass 2: one block per bucket. Count pr.x in LDS -> per-node deg/dis and
// inclusive-end ptr via block scan (bucket node-ranges are contiguous and in
// node order, so bucket pair-region base == global row prefix). Then bin into
// LDS image and write ecol coalesced. Replaces the old deg/scan pipeline.
__global__ __launch_bounds__(256) void k_bin2(const int* __restrict__ bstart,
                                              const int* __restrict__ pairs,
                                              int* __restrict__ ecol,
                                              int* __restrict__ ptr,
                                              int* __restrict__ deg,
                                              float* __restrict__ dis) {
  __shared__ int img[BIN_CAP];
  __shared__ int cnt[1024];
  __shared__ int cur[1024];
  __shared__ int ws[4];
  const int b = blockIdx.x;
  const int tid = threadIdx.x;
  const int lane = tid & 63, wid = tid >> 6;
  const int lo = bucket_lo(b), hi = bucket_hi(b), nn = hi - lo;
  const int base = bstart[b];
  const int n = bstart[b + 1] - base;
  for (int i = tid; i < 1024; i += 256) cnt[i] = 0;
  __syncthreads();
  const int2* __restrict__ p2 = (const int2*)pairs;
  for (int j = tid; j < n; j += 256) {
    const int2 pr = p2[base + j];
    atomicAdd(&cnt[pr.x - lo], 1);
  }
  __syncthreads();
  // block exclusive scan over cnt[0..1024): 4 values/thread + wave/block scan
  const int i0 = tid * 4;
  const int v0 = cnt[i0], v1 = cnt[i0 + 1], v2 = cnt[i0 + 2], v3 = cnt[i0 + 3];
  const int s4 = v0 + v1 + v2 + v3;
  int inc = s4;
#pragma unroll
  for (int s = 1; s < 64; s <<= 1) { int t = __shfl_up(inc, s); if (lane >= s) inc += t; }
  if (lane == 63) ws[wid] = inc;
  __syncthreads();
  int woff = 0;
  for (int w = 0; w < wid; ++w) woff += ws[w];
  int pre = woff + inc - s4;
  const int vv[4] = { v0, v1, v2, v3 };
#pragma unroll
  for (int k = 0; k < 4; ++k) {
    const int i = i0 + k;
    if (i < nn) {
      const int node = lo + i;
      cur[i] = pre;
      deg[node] = vv[k];
      dis[node] = 1.0f / sqrtf((float)(vv[k] > 0 ? vv[k] : 1));
      ptr[node] = base + pre + vv[k];        // inclusive end of row
    }
    pre += vv[k];
  }
  __syncthreads();
  for (int j = tid; j < n; j += 256) {
    const int2 pr = p2[base + j];
    const int p = atomicAdd(&cur[pr.x - lo], 1);
    img[p] = pr.y;
  }
  __syncthreads();
  for (int j = tid; j < n; j += 256) ecol[base + j] = img[j];
}

// Z0 = dis * concat(user_emb, item_emb), float4-wide
__global__ __launch_bounds__(256) void k_init(const float* __restrict__ ue,
                                              const float* __restrict__ ie,
                                              const float* __restrict__ dis,
                                              float* __restrict__ Z) {
  const int idx = blockIdx.x * blockDim.x + threadIdx.x; // float4 index
  if (idx >= N_NODES * 16) return;
  float4 v = (idx < USER_COUNT * 16) ? ((const float4*)ue)[idx]
                                     : ((const float4*)ie)[idx - USER_COUNT * 16];
  const float d = dis[idx >> 4];
  v.x *= d; v.y *= d; v.z *= d; v.w *= d;
  ((float4*)Z)[idx] = v;
}

// One wave per output row, Z-iteration gather-sum; 32 gathers in flight.
// fp32 throughout (R8: narrow Z flips sign(ego) -> fails). All shapes tried
// plateau at ~3.3 TB/s L2-fill for the random gather; time ~= FETCH/3.3TB/s.
template <int NOISE>
__global__ __launch_bounds__(256) void k_spmm(const int* __restrict__ ptr,
                                              const int* __restrict__ ecol,
                                              const float* __restrict__ dis,
                                              const float* __restrict__ Z,
                                              float* __restrict__ Zout,
                                              uint32_t k0, uint32_t k1) {
  const int w = (blockIdx.x * blockDim.x + threadIdx.x) >> 6;
  const int lane = threadIdx.x & 63;
  if (w >= N_NODES) return;
  const int g   = lane >> 4;
  const int sub = lane & 15;
  const int e1 = ptr[w];
  const int e0 = (w > 0) ? ptr[w - 1] : 0;
  const float4* __restrict__ Z4 = (const float4*)Z;

  float ax = 0.f, ay = 0.f, az = 0.f, aq = 0.f;
  for (int j = e0 + g; j < e1; j += 32) {
    int  cc[8];
    bool ok[8];
#pragma unroll
    for (int s = 0; s < 8; ++s) {
      const int js = j + 4 * s;
      ok[s] = js < e1;
      cc[s] = __builtin_nontemporal_load(ecol + (ok[s] ? js : j));
    }
    float4 xv[8];
#pragma unroll
    for (int s = 0; s < 8; ++s) xv[s] = Z4[cc[s] * 16 + sub];
#pragma unroll
    for (int s = 0; s < 8; ++s) {
      const float m = ok[s] ? 1.f : 0.f;
      ax = fmaf(m, xv[s].x, ax); ay = fmaf(m, xv[s].y, ay);
      az = fmaf(m, xv[s].z, az); aq = fmaf(m, xv[s].w, aq);
    }
  }
  ax += __shfl_xor(ax, 16); ax += __shfl_xor(ax, 32);
  ay += __shfl_xor(ay, 16); ay += __shfl_xor(ay, 32);
  az += __shfl_xor(az, 16); az += __shfl_xor(az, 32);
  aq += __shfl_xor(aq, 16); aq += __shfl_xor(aq, 32);

  const float dw = dis[w];
  float z0, z1, z2, z3;
  if (NOISE) {
    float v0 = dw * ax, v1 = dw * ay, v2 = dw * az, v3 = dw * aq;
    uint32_t t0 = 0u, t1 = (uint32_t)(w * EMB + sub * 4 + g);
    threefry2x32(k0, k1, t0, t1);
    const uint32_t bits = t0 ^ t1;
    const float u = __uint_as_float((bits >> 9) | 0x3f800000u) - 1.0f;
    float ss = u * u;
#pragma unroll
    for (int s = 1; s < 64; s <<= 1) ss += __shfl_xor(ss, s);
    const float inv = 1.0f / fmaxf(sqrtf(ss), 1e-12f);
    const float u0 = __shfl(u, sub);
    const float u1 = __shfl(u, 16 + sub);
    const float u2 = __shfl(u, 32 + sub);
    const float u3 = __shfl(u, 48 + sub);
    const float e = EPS_F * inv;
    v0 = fmaf(((v0 > 0.f) ? 1.f : ((v0 < 0.f) ? -1.f : 0.f)) * u0, e, v0);
    v1 = fmaf(((v1 > 0.f) ? 1.f : ((v1 < 0.f) ? -1.f : 0.f)) * u1, e, v1);
    v2 = fmaf(((v2 > 0.f) ? 1.f : ((v2 < 0.f) ? -1.f : 0.f)) * u2, e, v2);
    v3 = fmaf(((v3 > 0.f) ? 1.f : ((v3 < 0.f) ? -1.f : 0.f)) * u3, e, v3);
    z0 = dw * v0; z1 = dw * v1; z2 = dw * v2; z3 = dw * v3;
  } else {
    const float d2 = dw * dw;
    z0 = d2 * ax; z1 = d2 * ay; z2 = d2 * az; z3 = d2 * aq;
  }
  if (g == 0) {
    float4 r; r.x = z0; r.y = z1; r.z = z2; r.w = z3;
    ((float4*)Zout)[w * 16 + sub] = r;
  }
}

// Final noisy layer (k=2): only batch rows needed -> fused spmm+noise+mean.
__global__ __launch_bounds__(256) void k_spmm_last(const int* __restrict__ ptr,
                                                   const int* __restrict__ ecol,
                                                   const float* __restrict__ dis,
                                                   const float* __restrict__ Z,
                                                   const int* __restrict__ users,
                                                   const int* __restrict__ items,
                                                   float* __restrict__ out_u,
                                                   float* __restrict__ out_i,
                                                   uint32_t k0, uint32_t k1) {
  const int b = (blockIdx.x * blockDim.x + threadIdx.x) >> 6;
  const int lane = threadIdx.x & 63;
  if (b >= 2 * BATCH) return;
  const int g   = lane >> 4;
  const int sub = lane & 15;
  int w; float* dst;
  if (b < BATCH) { w = users[b];                      dst = out_u + (size_t)b * EMB; }
  else           { w = USER_COUNT + items[b - BATCH]; dst = out_i + (size_t)(b - BATCH) * EMB; }
  const int e1 = ptr[w];
  const int e0 = (w > 0) ? ptr[w - 1] : 0;
  const float4* __restrict__ Z4 = (const float4*)Z;

  float ax = 0.f, ay = 0.f, az = 0.f, aq = 0.f;
  for (int j = e0 + g; j < e1; j += 32) {
    int  cc[8];
    bool ok[8];
#pragma unroll
    for (int s = 0; s < 8; ++s) {
      const int js = j + 4 * s;
      ok[s] = js < e1;
      cc[s] = __builtin_nontemporal_load(ecol + (ok[s] ? js : j));
    }
    float4 xv[8];
#pragma unroll
    for (int s = 0; s < 8; ++s) xv[s] = Z4[cc[s] * 16 + sub];
#pragma unroll
    for (int s = 0; s < 8; ++s) {
      const float m = ok[s] ? 1.f : 0.f;
      ax = fmaf(m, xv[s].x, ax); ay = fmaf(m, xv[s].y, ay);
      az = fmaf(m, xv[s].z, az); aq = fmaf(m, xv[s].w, aq);
    }
  }
  ax += __shfl_xor(ax, 16); ax += __shfl_xor(ax, 32);
  ay += __shfl_xor(ay, 16); ay += __shfl_xor(ay, 32);
  az += __shfl_xor(az, 16); az += __shfl_xor(az, 32);
  aq += __shfl_xor(aq, 16); aq += __shfl_xor(aq, 32);

  const float dw = dis[w];
  float v0 = dw * ax, v1 = dw * ay, v2 = dw * az, v3 = dw * aq;
  uint32_t t0 = 0u, t1 = (uint32_t)(w * EMB + sub * 4 + g);
  threefry2x32(k0, k1, t0, t1);
  const uint32_t bits = t0 ^ t1;
  const float u = __uint_as_float((bits >> 9) | 0x3f800000u) - 1.0f;
  float ss = u * u;
#pragma unroll
  for (int s = 1; s < 64; s <<= 1) ss += __shfl_xor(ss, s);
  const float inv = 1.0f / fmaxf(sqrtf(ss), 1e-12f);
  const float u0 = __shfl(u, sub);
  const float u1 = __shfl(u, 16 + sub);
  const float u2 = __shfl(u, 32 + sub);
  const float u3 = __shfl(u, 48 + sub);
  const float e = EPS_F * inv;
  v0 = fmaf(((v0 > 0.f) ? 1.f : ((v0 < 0.f) ? -1.f : 0.f)) * u0, e, v0);
  v1 = fmaf(((v1 > 0.f) ? 1.f : ((v1 < 0.f) ? -1.f : 0.f)) * u1, e, v1);
  v2 = fmaf(((v2 > 0.f) ? 1.f : ((v2 < 0.f) ? -1.f : 0.f)) * u2, e, v2);
  v3 = fmaf(((v3 > 0.f) ? 1.f : ((v3 < 0.f) ? -1.f : 0.f)) * u3, e, v3);

  if (g == 0) {
    float4 o = ((float4*)dst)[sub];
    o.x += v0 * (1.0f / 3.0f); o.y += v1 * (1.0f / 3.0f);
    o.z += v2 * (1.0f / 3.0f); o.w += v3 * (1.0f / 3.0f);
    ((float4*)dst)[sub] = o;
  }
}

// gather batch rows from Z, recovering ego = Z * sqrt(max(deg,1))
__global__ __launch_bounds__(256) void k_gather(const float* __restrict__ Z,
                                                const int* __restrict__ deg,
                                                const int* __restrict__ users,
                                                const int* __restrict__ items,
                                                float* __restrict__ out_u,
                                                float* __restrict__ out_i,
                                                float* __restrict__ cl_u,
                                                float* __restrict__ cl_i,
                                                float scale, int init) {
  const int w = (blockIdx.x * blockDim.x + threadIdx.x) >> 6;
  const int lane = threadIdx.x & 63;
  if (w >= 2 * BATCH) return;
  int src; float* dst; float* dst2;
  if (w < BATCH) {
    src = users[w];               dst = out_u + w * EMB;
    dst2 = cl_u ? cl_u + w * EMB : nullptr;
  } else {
    int q = w - BATCH;
    src = USER_COUNT + items[q];  dst = out_i + q * EMB;
    dst2 = cl_i ? cl_i + q * EMB : nullptr;
  }
  const int d = deg[src];
  const float rdis = sqrtf((float)(d > 0 ? d : 1));
  float raw = Z[(size_t)src * EMB + lane] * rdis;
  float v = raw * scale;
  dst[lane] = init ? v : (dst[lane] + v);
  if (dst2) dst2[lane] = raw;
}

extern "C" void kernel_launch(void* const* d_in, const int* in_sizes, int n_in,
                              void* d_out, int out_size, void* d_ws, size_t ws_size,
                              hipStream_t stream) {
  const float* user_emb = (const float*)d_in[0];
  const float* item_emb = (const float*)d_in[1];
  // d_in[2] = vals: unused, recomputed bit-identically from degrees
  const int* rows  = (const int*)d_in[3];
  const int* cols  = (const int*)d_in[4];
  const int* users = (const int*)d_in[5];
  const int* items = (const int*)d_in[6];

  float* X   = (float*)d_ws;                       // 9.6M f32 (Z ping)
  float* Y   = X + (size_t)N_NODES * EMB;          // 9.6M f32 (Z pong)
  int*   deg = (int*)(Y + (size_t)N_NODES * EMB);  // 150k
  int*   ptr = deg + N_NODES;                      // 150k
  float* dis = (float*)(ptr + N_NODES);            // 150k
  int*   ecol = (int*)(dis + N_NODES);             // 4M
  int*   bkcnt = ecol + N_EDGES;                   // 196
  int*   bstart = bkcnt + 256;                     // 197
  int*   bcur = bstart + 256;                      // 196
  int*   pairs = (int*)Y;                          // 8M ints, aliases Y (dead
                                                   // until first spmm output)

  float* out  = (float*)d_out;
  float* u_all = out;
  float* i_all = out + (size_t)BATCH * EMB;
  float* u_tr  = out + (size_t)2 * BATCH * EMB;
  float* i_tr  = out + (size_t)3 * BATCH * EMB;
  float* u_cl  = out + (size_t)4 * BATCH * EMB;
  float* i_cl  = out + (size_t)5 * BATCH * EMB;

  // ---- build CSR: bucket-hist -> scan -> LDS-staged counting sort ----
  hipMemsetAsync(bkcnt, 0, sizeof(int) * 256, stream);
  k_bkhist<<<1024, 256, 0, stream>>>(rows, cols, bkcnt);
  k_bkscan<<<1, 64, 0, stream>>>(bkcnt, bstart, bcur);
  k_p1<<<NBLK1, 256, 0, stream>>>(rows, cols, bcur, pairs);
  k_bin2<<<NBK, 256, 0, stream>>>(bstart, pairs, ecol, ptr, deg, dis);

  // ---- Z0 = dis * concat(user_emb, item_emb) ----
  k_init<<<(N_NODES * 16 + 255) / 256, 256, 0, stream>>>(user_emb, item_emb, dis, X);

  const int spmm_grid = (N_NODES * EMB + 255) / 256; // 37500
  const int gat_grid  = (2 * BATCH * EMB + 255) / 256; // 2048

  // ---- phase 1: 3 clean layers, mean-gather into outputs 0,1 ----
  for (int l = 0; l < 3; ++l) {
    k_spmm<0><<<spmm_grid, 256, 0, stream>>>(ptr, ecol, dis, X, Y, 0u, 0u);
    k_gather<<<gat_grid, 256, 0, stream>>>(Y, deg, users, items, u_all, i_all,
                                           nullptr, nullptr, 1.0f / 3.0f, l == 0);
    float* t = X; X = Y; Y = t;
  }

  // ---- phase 2: noisy layers k=0,1 full-width; k=2 batch-rows-only fused ----
  for (int k = 0; k < 2; ++k) {
    uint32_t f0 = 0u, f1 = (uint32_t)k;      // fold_in(key(42), k)
    threefry2x32(0u, 42u, f0, f1);
    k_spmm<1><<<spmm_grid, 256, 0, stream>>>(ptr, ecol, dis, X, Y, f0, f1);
    k_gather<<<gat_grid, 256, 0, stream>>>(Y, deg, users, items, u_tr, i_tr,
                                           (k == 0) ? u_cl : nullptr,
                                           (k == 0) ? i_cl : nullptr,
                                           1.0f / 3.0f, k == 0);
    float* t = X; X = Y; Y = t;
  }
  {
    uint32_t f0 = 0u, f1 = 2u;               // fold_in(key(42), 2)
    threefry2x32(0u, 42u, f0, f1);
    k_spmm_last<<<gat_grid, 256, 0, stream>>>(ptr, ecol, dis, X, users, items,
                                              u_tr, i_tr, f0, f1);
  }
}

// Round 15
// 788.805 us; speedup vs baseline: 3.5437x; 1.0964x over previous
//
#include <hip/hip_runtime.h>
#include <stdint.h>

#define USER_COUNT 100000
#define ITEM_COUNT 50000
#define N_NODES    150000
#define EMB        64
#define N_EDGES    4000000
#define BATCH      4096
#define EPS_F      0.2f

// ---- bucket geometry: degree-balanced (users deg~20 get 1024 nodes,
// items deg~40 get 512 nodes -> ~20K edges per bucket uniformly) ----
#define UBKN 98                  // ceil(100000/1024)
#define IBKN 98                  // ceil(50000/512)
#define NBK  (UBKN + IBKN)       // 196
#define FIFO_CAP 32
#define NBLK1 1024
#define EROUND 512               // edges per round (2 per thread)
#define CHUNK ((N_EDGES / 2 + NBLK1 - 1) / NBLK1)  // 1954
#define BIN_CAP 24576            // 96KB LDS image; max bucket ~21K edges

typedef int int4v __attribute__((ext_vector_type(4)));

__device__ inline int bucket_of(int n) {
  return (n < USER_COUNT) ? (n >> 10) : (UBKN + ((n - USER_COUNT) >> 9));
}
__device__ inline int bucket_lo(int b) {
  return (b < UBKN) ? (b << 10) : (USER_COUNT + ((b - UBKN) << 9));
}
__device__ inline int bucket_hi(int b) {
  int hi = (b < UBKN) ? ((b + 1) << 10) : (USER_COUNT + ((b - UBKN + 1) << 9));
  int cap = (b < UBKN) ? USER_COUNT : N_NODES;
  return hi < cap ? hi : cap;
}
// pack (local-row-in-bucket [10b], neighbor node [18b]) into one u32:
// halves pair traffic + FIFO LDS vs (int,int).
__device__ inline uint32_t pack_pair(int a, int bnode) {
  const int lrow = (a < USER_COUNT) ? (a & 1023) : ((a - USER_COUNT) & 511);
  return ((uint32_t)lrow << 18) | (uint32_t)bnode;
}

// ---- JAX threefry-2x32 (20 rounds), bit-exact ----
__host__ __device__ inline void threefry2x32(uint32_t k0, uint32_t k1,
                                             uint32_t& x0, uint32_t& x1) {
  const uint32_t ks2 = k0 ^ k1 ^ 0x1BD11BDAu;
  x0 += k0; x1 += k1;
#define TF_ROT(r) { x0 += x1; x1 = (x1 << (r)) | (x1 >> (32 - (r))); x1 ^= x0; }
  TF_ROT(13) TF_ROT(15) TF_ROT(26) TF_ROT(6)
  x0 += k1;  x1 += ks2 + 1u;
  TF_ROT(17) TF_ROT(29) TF_ROT(16) TF_ROT(24)
  x0 += ks2; x1 += k0 + 2u;
  TF_ROT(13) TF_ROT(15) TF_ROT(26) TF_ROT(6)
  x0 += k0;  x1 += k1 + 3u;
  TF_ROT(17) TF_ROT(29) TF_ROT(16) TF_ROT(24)
  x0 += k1;  x1 += ks2 + 4u;
  TF_ROT(13) TF_ROT(15) TF_ROT(26) TF_ROT(6)
  x0 += ks2; x1 += k0 + 5u;
#undef TF_ROT
}

// Bucket histogram: 196 LDS bins per block, one global atomic per bin per
// block. (R13 lesson: 8M global atomics = 160us of coherence traffic.)
__global__ __launch_bounds__(256) void k_bkhist(const int* __restrict__ rows,
                                                const int* __restrict__ cols,
                                                int* __restrict__ bkcnt) {
  __shared__ int h[NBK];
  for (int i = threadIdx.x; i < NBK; i += 256) h[i] = 0;
  __syncthreads();
  const int stride = gridDim.x * blockDim.x;
  for (int e = blockIdx.x * blockDim.x + threadIdx.x; e < N_EDGES / 2; e += stride) {
    const int r = __builtin_nontemporal_load(rows + e);
    const int c = __builtin_nontemporal_load(cols + e);
    atomicAdd(&h[bucket_of(r)], 1);
    atomicAdd(&h[bucket_of(c)], 1);
  }
  __syncthreads();
  for (int i = threadIdx.x; i < NBK; i += 256)
    if (h[i]) atomicAdd(&bkcnt[i], h[i]);
}

// 1-wave exclusive scan of bucket counts -> bstart[0..NBK] and bcur init.
__global__ void k_bkscan(const int* __restrict__ bkcnt, int* __restrict__ bstart,
                         int* __restrict__ bcur) {
  const int lane = threadIdx.x; // blockDim = 64
  int carry = 0;
  for (int base = 0; base < NBK; base += 64) {
    const int idx = base + lane;
    int v = (idx < NBK) ? bkcnt[idx] : 0;
    int inc = v;
#pragma unroll
    for (int s = 1; s < 64; s <<= 1) { int t = __shfl_up(inc, s); if (lane >= s) inc += t; }
    if (idx < NBK) { bstart[idx] = inc - v + carry; bcur[idx] = inc - v + carry; }
    carry += __shfl(inc, 63);
  }
  if (lane == 0) bstart[NBK] = carry;   // == N_EDGES
}

// Pass 1: stream first 2M (r,c); insert packed (r->bkt(r)) and (c->bkt(c))
// into LDS ring-FIFOs; flush 16-pair (64B) contiguous runs via one
// global-cursor atomic per run. Coalesced writes beat the no-write-allocate
// L2 (scattered 4B stores cost a full line each — R6/R9/R11).
__global__ __launch_bounds__(256) void k_p1(const int* __restrict__ rows,
                                            const int* __restrict__ cols,
                                            int* __restrict__ bcur,
                                            uint32_t* __restrict__ pairs) {
  __shared__ uint32_t fifo[NBK * FIFO_CAP];
  __shared__ int cnt[NBK], tail[NBK], rc[NBK];
  __shared__ int wlB[NBK], wlG[NBK], wlT[NBK], wlM[NBK];
  __shared__ unsigned char ovf[NBK];
  __shared__ int wlN;
  const int tid = threadIdx.x;
  for (int b = tid; b < NBK; b += 256) { cnt[b] = 0; tail[b] = 0; }
  const int eStart = blockIdx.x * CHUNK;
  const int eEnd = (eStart + CHUNK < N_EDGES / 2) ? eStart + CHUNK : N_EDGES / 2;
  for (int base = eStart; base < eEnd; base += EROUND) {
    int rr[2], cc2[2];
    bool val[2];
#pragma unroll
    for (int q = 0; q < 2; ++q) {
      const int e = base + q * 256 + tid;
      val[q] = e < eEnd;
      if (val[q]) { rr[q] = __builtin_nontemporal_load(rows + e);
                    cc2[q] = __builtin_nontemporal_load(cols + e); }
    }
    for (int b = tid; b < NBK; b += 256) rc[b] = 0;
    if (tid == 0) wlN = 0;
    __syncthreads();
#pragma unroll
    for (int q = 0; q < 2; ++q)
      if (val[q]) { atomicAdd(&rc[bucket_of(rr[q])], 1);
                    atomicAdd(&rc[bucket_of(cc2[q])], 1); }
    __syncthreads();
    for (int b = tid; b < NBK; b += 256)
      ovf[b] = (cnt[b] - tail[b] + rc[b] > FIFO_CAP) ? 1 : 0;
    __syncthreads();
#pragma unroll
    for (int q = 0; q < 2; ++q) {
      if (val[q]) {
#pragma unroll
        for (int dir = 0; dir < 2; ++dir) {
          const int a = dir ? cc2[q] : rr[q], bnode = dir ? rr[q] : cc2[q];
          const int bb = bucket_of(a);
          const uint32_t pk = pack_pair(a, bnode);
          if (ovf[bb]) {
            int g = atomicAdd(&bcur[bb], 1);
            pairs[g] = pk;                              // rare spill
          } else {
            int idx = atomicAdd(&cnt[bb], 1);
            fifo[bb * FIFO_CAP + (idx & (FIFO_CAP - 1))] = pk;
          }
        }
      }
    }
    __syncthreads();
    for (int b = tid; b < NBK; b += 256) {
      int m = (cnt[b] - tail[b]) & ~15;                 // 0,16,32
      if (m > 0) {
        int g = atomicAdd(&bcur[b], m);
        int w = atomicAdd(&wlN, 1);
        wlB[w] = b; wlG[w] = g; wlT[w] = tail[b]; wlM[w] = m;
        tail[b] += m;
      }
    }
    __syncthreads();
    const int nw = wlN;
    for (int j = tid; j < nw * FIFO_CAP; j += 256) {
      const int wi = j / FIFO_CAP, k = j % FIFO_CAP;
      if (k < wlM[wi]) {
        const int b = wlB[wi];
        const int s = (wlT[wi] + k) & (FIFO_CAP - 1);
        pairs[wlG[wi] + k] = fifo[b * FIFO_CAP + s];
      }
    }
    __syncthreads();
  }
  // final drain (<=31 pairs per bucket)
  for (int b = tid; b < NBK; b += 256) {
    const int m = cnt[b] - tail[b];
    if (m > 0) {
      int g = atomicAdd(&bcur[b], m);
      for (int k = 0; k < m; ++k)
        pairs[g + k] = fifo[b * FIFO_CAP + ((tail[b] + k) & (FIFO_CAP - 1))];
    }
  }
}

// Pass 2: one block per bucket. Count lrow in LDS -> per-node deg/dis and
// inclusive-end ptr via block scan (bucket pair-region base == global row
// prefix), then bin into LDS image and write ecol coalesced.
__global__ __launch_bounds__(256) void k_bin2(const int* __restrict__ bstart,
                                              const uint32_t* __restrict__ pairs,
                                              int* __restrict__ ecol,
                                              int* __restrict__ ptr,
                                              int* __restrict__ deg,
                                              float* __restrict__ dis) {
  __shared__ int img[BIN_CAP];
  __shared__ int cnt[1024];
  __shared__ int cur[1024];
  __shared__ int ws[4];
  const int b = blockIdx.x;
  const int tid = threadIdx.x;
  const int lane = tid & 63, wid = tid >> 6;
  const int lo = bucket_lo(b), hi = bucket_hi(b), nn = hi - lo;
  const int base = bstart[b];
  const int n = bstart[b + 1] - base;
  for (int i = tid; i < 1024; i += 256) cnt[i] = 0;
  __syncthreads();
  for (int j = tid; j < n; j += 256)
    atomicAdd(&cnt[pairs[base + j] >> 18], 1);
  __syncthreads();
  // block exclusive scan over cnt[0..1024): 4 values/thread + wave/block scan
  const int i0 = tid * 4;
  const int v0 = cnt[i0], v1 = cnt[i0 + 1], v2 = cnt[i0 + 2], v3 = cnt[i0 + 3];
  const int s4 = v0 + v1 + v2 + v3;
  int inc = s4;
#pragma unroll
  for (int s = 1; s < 64; s <<= 1) { int t = __shfl_up(inc, s); if (lane >= s) inc += t; }
  if (lane == 63) ws[wid] = inc;
  __syncthreads();
  int woff = 0;
  for (int w = 0; w < wid; ++w) woff += ws[w];
  int pre = woff + inc - s4;
  const int vv[4] = { v0, v1, v2, v3 };
#pragma unroll
  for (int k = 0; k < 4; ++k) {
    const int i = i0 + k;
    if (i < nn) {
      const int node = lo + i;
      cur[i] = pre;
      deg[node] = vv[k];
      dis[node] = 1.0f / sqrtf((float)(vv[k] > 0 ? vv[k] : 1));
      ptr[node] = base + pre + vv[k];        // inclusive end of row
    }
    pre += vv[k];
  }
  __syncthreads();
  for (int j = tid; j < n; j += 256) {
    const uint32_t pr = pairs[base + j];
    const int p = atomicAdd(&cur[pr >> 18], 1);
    img[p] = (int)(pr & 0x3FFFFu);
  }
  __syncthreads();
  for (int j = tid; j < n; j += 256) ecol[base + j] = img[j];
}

// Z0 = dis * concat(user_emb, item_emb), float4-wide
__global__ __launch_bounds__(256) void k_init(const float* __restrict__ ue,
                                              const float* __restrict__ ie,
                                              const float* __restrict__ dis,
                                              float* __restrict__ Z) {
  const int idx = blockIdx.x * blockDim.x + threadIdx.x; // float4 index
  if (idx >= N_NODES * 16) return;
  float4 v = (idx < USER_COUNT * 16) ? ((const float4*)ue)[idx]
                                     : ((const float4*)ie)[idx - USER_COUNT * 16];
  const float d = dis[idx >> 4];
  v.x *= d; v.y *= d; v.z *= d; v.w *= d;
  ((float4*)Z)[idx] = v;
}

// One wave per output row, Z-iteration gather-sum; 32 gathers in flight.
// fp32 throughout (R8: narrow Z flips sign(ego) -> fails). All shapes tried
// plateau at ~3.3 TB/s L2-fill for the random gather; time ~= FETCH/3.3TB/s.
template <int NOISE>
__global__ __launch_bounds__(256) void k_spmm(const int* __restrict__ ptr,
                                              const int* __restrict__ ecol,
                                              const float* __restrict__ dis,
                                              const float* __restrict__ Z,
                                              float* __restrict__ Zout,
                                              uint32_t k0, uint32_t k1) {
  const int w = (blockIdx.x * blockDim.x + threadIdx.x) >> 6;
  const int lane = threadIdx.x & 63;
  if (w >= N_NODES) return;
  const int g   = lane >> 4;
  const int sub = lane & 15;
  const int e1 = ptr[w];
  const int e0 = (w > 0) ? ptr[w - 1] : 0;
  const float4* __restrict__ Z4 = (const float4*)Z;

  float ax = 0.f, ay = 0.f, az = 0.f, aq = 0.f;
  for (int j = e0 + g; j < e1; j += 32) {
    int  cc[8];
    bool ok[8];
#pragma unroll
    for (int s = 0; s < 8; ++s) {
      const int js = j + 4 * s;
      ok[s] = js < e1;
      cc[s] = __builtin_nontemporal_load(ecol + (ok[s] ? js : j));
    }
    float4 xv[8];
#pragma unroll
    for (int s = 0; s < 8; ++s) xv[s] = Z4[cc[s] * 16 + sub];
#pragma unroll
    for (int s = 0; s < 8; ++s) {
      const float m = ok[s] ? 1.f : 0.f;
      ax = fmaf(m, xv[s].x, ax); ay = fmaf(m, xv[s].y, ay);
      az = fmaf(m, xv[s].z, az); aq = fmaf(m, xv[s].w, aq);
    }
  }
  ax += __shfl_xor(ax, 16); ax += __shfl_xor(ax, 32);
  ay += __shfl_xor(ay, 16); ay += __shfl_xor(ay, 32);
  az += __shfl_xor(az, 16); az += __shfl_xor(az, 32);
  aq += __shfl_xor(aq, 16); aq += __shfl_xor(aq, 32);

  const float dw = dis[w];
  float z0, z1, z2, z3;
  if (NOISE) {
    float v0 = dw * ax, v1 = dw * ay, v2 = dw * az, v3 = dw * aq;
    uint32_t t0 = 0u, t1 = (uint32_t)(w * EMB + sub * 4 + g);
    threefry2x32(k0, k1, t0, t1);
    const uint32_t bits = t0 ^ t1;
    const float u = __uint_as_float((bits >> 9) | 0x3f800000u) - 1.0f;
    float ss = u * u;
#pragma unroll
    for (int s = 1; s < 64; s <<= 1) ss += __shfl_xor(ss, s);
    const float inv = 1.0f / fmaxf(sqrtf(ss), 1e-12f);
    const float u0 = __shfl(u, sub);
    const float u1 = __shfl(u, 16 + sub);
    const float u2 = __shfl(u, 32 + sub);
    const float u3 = __shfl(u, 48 + sub);
    const float e = EPS_F * inv;
    v0 = fmaf(((v0 > 0.f) ? 1.f : ((v0 < 0.f) ? -1.f : 0.f)) * u0, e, v0);
    v1 = fmaf(((v1 > 0.f) ? 1.f : ((v1 < 0.f) ? -1.f : 0.f)) * u1, e, v1);
    v2 = fmaf(((v2 > 0.f) ? 1.f : ((v2 < 0.f) ? -1.f : 0.f)) * u2, e, v2);
    v3 = fmaf(((v3 > 0.f) ? 1.f : ((v3 < 0.f) ? -1.f : 0.f)) * u3, e, v3);
    z0 = dw * v0; z1 = dw * v1; z2 = dw * v2; z3 = dw * v3;
  } else {
    const float d2 = dw * dw;
    z0 = d2 * ax; z1 = d2 * ay; z2 = d2 * az; z3 = d2 * aq;
  }
  if (g == 0) {
    float4 r; r.x = z0; r.y = z1; r.z = z2; r.w = z3;
    ((float4*)Zout)[w * 16 + sub] = r;
  }
}

// Final noisy layer (k=2): only batch rows needed -> fused spmm+noise+mean.
__global__ __launch_bounds__(256) void k_spmm_last(const int* __restrict__ ptr,
                                                   const int* __restrict__ ecol,
                                                   const float* __restrict__ dis,
                                                   const float* __restrict__ Z,
                                                   const int* __restrict__ users,
                                                   const int* __restrict__ items,
                                                   float* __restrict__ out_u,
                                                   float* __restrict__ out_i,
                                                   uint32_t k0, uint32_t k1) {
  const int b = (blockIdx.x * blockDim.x + threadIdx.x) >> 6;
  const int lane = threadIdx.x & 63;
  if (b >= 2 * BATCH) return;
  const int g   = lane >> 4;
  const int sub = lane & 15;
  int w; float* dst;
  if (b < BATCH) { w = users[b];                      dst = out_u + (size_t)b * EMB; }
  else           { w = USER_COUNT + items[b - BATCH]; dst = out_i + (size_t)(b - BATCH) * EMB; }
  const int e1 = ptr[w];
  const int e0 = (w > 0) ? ptr[w - 1] : 0;
  const float4* __restrict__ Z4 = (const float4*)Z;

  float ax = 0.f, ay = 0.f, az = 0.f, aq = 0.f;
  for (int j = e0 + g; j < e1; j += 32) {
    int  cc[8];
    bool ok[8];
#pragma unroll
    for (int s = 0; s < 8; ++s) {
      const int js = j + 4 * s;
      ok[s] = js < e1;
      cc[s] = __builtin_nontemporal_load(ecol + (ok[s] ? js : j));
    }
    float4 xv[8];
#pragma unroll
    for (int s = 0; s < 8; ++s) xv[s] = Z4[cc[s] * 16 + sub];
#pragma unroll
    for (int s = 0; s < 8; ++s) {
      const float m = ok[s] ? 1.f : 0.f;
      ax = fmaf(m, xv[s].x, ax); ay = fmaf(m, xv[s].y, ay);
      az = fmaf(m, xv[s].z, az); aq = fmaf(m, xv[s].w, aq);
    }
  }
  ax += __shfl_xor(ax, 16); ax += __shfl_xor(ax, 32);
  ay += __shfl_xor(ay, 16); ay += __shfl_xor(ay, 32);
  az += __shfl_xor(az, 16); az += __shfl_xor(az, 32);
  aq += __shfl_xor(aq, 16); aq += __shfl_xor(aq, 32);

  const float dw = dis[w];
  float v0 = dw * ax, v1 = dw * ay, v2 = dw * az, v3 = dw * aq;
  uint32_t t0 = 0u, t1 = (uint32_t)(w * EMB + sub * 4 + g);
  threefry2x32(k0, k1, t0, t1);
  const uint32_t bits = t0 ^ t1;
  const float u = __uint_as_float((bits >> 9) | 0x3f800000u) - 1.0f;
  float ss = u * u;
#pragma unroll
  for (int s = 1; s < 64; s <<= 1) ss += __shfl_xor(ss, s);
  const float inv = 1.0f / fmaxf(sqrtf(ss), 1e-12f);
  const float u0 = __shfl(u, sub);
  const float u1 = __shfl(u, 16 + sub);
  const float u2 = __shfl(u, 32 + sub);
  const float u3 = __shfl(u, 48 + sub);
  const float e = EPS_F * inv;
  v0 = fmaf(((v0 > 0.f) ? 1.f : ((v0 < 0.f) ? -1.f : 0.f)) * u0, e, v0);
  v1 = fmaf(((v1 > 0.f) ? 1.f : ((v1 < 0.f) ? -1.f : 0.f)) * u1, e, v1);
  v2 = fmaf(((v2 > 0.f) ? 1.f : ((v2 < 0.f) ? -1.f : 0.f)) * u2, e, v2);
  v3 = fmaf(((v3 > 0.f) ? 1.f : ((v3 < 0.f) ? -1.f : 0.f)) * u3, e, v3);

  if (g == 0) {
    float4 o = ((float4*)dst)[sub];
    o.x += v0 * (1.0f / 3.0f); o.y += v1 * (1.0f / 3.0f);
    o.z += v2 * (1.0f / 3.0f); o.w += v3 * (1.0f / 3.0f);
    ((float4*)dst)[sub] = o;
  }
}

// gather batch rows from Z, recovering ego = Z * sqrt(max(deg,1))
__global__ __launch_bounds__(256) void k_gather(const float* __restrict__ Z,
                                                const int* __restrict__ deg,
                                                const int* __restrict__ users,
                                                const int* __restrict__ items,
                                                float* __restrict__ out_u,
                                                float* __restrict__ out_i,
                                                float* __restrict__ cl_u,
                                                float* __restrict__ cl_i,
                                                float scale, int init) {
  const int w = (blockIdx.x * blockDim.x + threadIdx.x) >> 6;
  const int lane = threadIdx.x & 63;
  if (w >= 2 * BATCH) return;
  int src; float* dst; float* dst2;
  if (w < BATCH) {
    src = users[w];               dst = out_u + w * EMB;
    dst2 = cl_u ? cl_u + w * EMB : nullptr;
  } else {
    int q = w - BATCH;
    src = USER_COUNT + items[q];  dst = out_i + q * EMB;
    dst2 = cl_i ? cl_i + q * EMB : nullptr;
  }
  const int d = deg[src];
  const float rdis = sqrtf((float)(d > 0 ? d : 1));
  float raw = Z[(size_t)src * EMB + lane] * rdis;
  float v = raw * scale;
  dst[lane] = init ? v : (dst[lane] + v);
  if (dst2) dst2[lane] = raw;
}

extern "C" void kernel_launch(void* const* d_in, const int* in_sizes, int n_in,
                              void* d_out, int out_size, void* d_ws, size_t ws_size,
                              hipStream_t stream) {
  const float* user_emb = (const float*)d_in[0];
  const float* item_emb = (const float*)d_in[1];
  // d_in[2] = vals: unused, recomputed bit-identically from degrees
  const int* rows  = (const int*)d_in[3];
  const int* cols  = (const int*)d_in[4];
  const int* users = (const int*)d_in[5];
  const int* items = (const int*)d_in[6];

  float* X   = (float*)d_ws;                       // 9.6M f32 (Z ping)
  float* Y   = X + (size_t)N_NODES * EMB;          // 9.6M f32 (Z pong)
  int*   deg = (int*)(Y + (size_t)N_NODES * EMB);  // 150k
  int*   ptr = deg + N_NODES;                      // 150k
  float* dis = (float*)(ptr + N_NODES);            // 150k
  int*   ecol = (int*)(dis + N_NODES);             // 4M
  int*   bkcnt = ecol + N_EDGES;                   // 196
  int*   bstart = bkcnt + 256;                     // 197
  int*   bcur = bstart + 256;                      // 196
  uint32_t* pairs = (uint32_t*)Y;                  // 4M u32, aliases Y (dead
                                                   // until first spmm output)

  float* out  = (float*)d_out;
  float* u_all = out;
  float* i_all = out + (size_t)BATCH * EMB;
  float* u_tr  = out + (size_t)2 * BATCH * EMB;
  float* i_tr  = out + (size_t)3 * BATCH * EMB;
  float* u_cl  = out + (size_t)4 * BATCH * EMB;
  float* i_cl  = out + (size_t)5 * BATCH * EMB;

  // ---- build CSR: bucket-hist -> scan -> LDS-staged counting sort ----
  hipMemsetAsync(bkcnt, 0, sizeof(int) * 256, stream);
  k_bkhist<<<1024, 256, 0, stream>>>(rows, cols, bkcnt);
  k_bkscan<<<1, 64, 0, stream>>>(bkcnt, bstart, bcur);
  k_p1<<<NBLK1, 256, 0, stream>>>(rows, cols, bcur, pairs);
  k_bin2<<<NBK, 256, 0, stream>>>(bstart, pairs, ecol, ptr, deg, dis);

  // ---- Z0 = dis * concat(user_emb, item_emb) ----
  k_init<<<(N_NODES * 16 + 255) / 256, 256, 0, stream>>>(user_emb, item_emb, dis, X);

  const int spmm_grid = (N_NODES * EMB + 255) / 256; // 37500
  const int gat_grid  = (2 * BATCH * EMB + 255) / 256; // 2048

  // ---- phase 1: 3 clean layers, mean-gather into outputs 0,1 ----
  for (int l = 0; l < 3; ++l) {
    k_spmm<0><<<spmm_grid, 256, 0, stream>>>(ptr, ecol, dis, X, Y, 0u, 0u);
    k_gather<<<gat_grid, 256, 0, stream>>>(Y, deg, users, items, u_all, i_all,
                                           nullptr, nullptr, 1.0f / 3.0f, l == 0);
    float* t = X; X = Y; Y = t;
  }

  // ---- phase 2: noisy layers k=0,1 full-width; k=2 batch-rows-only fused ----
  for (int k = 0; k < 2; ++k) {
    uint32_t f0 = 0u, f1 = (uint32_t)k;      // fold_in(key(42), k)
    threefry2x32(0u, 42u, f0, f1);
    k_spmm<1><<<spmm_grid, 256, 0, stream>>>(ptr, ecol, dis, X, Y, f0, f1);
    k_gather<<<gat_grid, 256, 0, stream>>>(Y, deg, users, items, u_tr, i_tr,
                                           (k == 0) ? u_cl : nullptr,
                                           (k == 0) ? i_cl : nullptr,
                                           1.0f / 3.0f, k == 0);
    float* t = X; X = Y; Y = t;
  }
  {
    uint32_t f0 = 0u, f1 = 2u;               // fold_in(key(42), 2)
    threefry2x32(0u, 42u, f0, f1);
    k_spmm_last<<<gat_grid, 256, 0, stream>>>(ptr, ecol, dis, X, users, items,
                                              u_tr, i_tr, f0, f1);
  }
}

// Round 16
// 786.977 us; speedup vs baseline: 3.5520x; 1.0023x over previous
//
#include <hip/hip_runtime.h>
#include <stdint.h>

#define USER_COUNT 100000
#define ITEM_COUNT 50000
#define N_NODES    150000
#define EMB        64
#define N_EDGES    4000000
#define BATCH      4096
#define EPS_F      0.2f

// ---- bucket geometry: degree-balanced (users deg~20 get 1024 nodes,
// items deg~40 get 512 nodes -> ~20K edges per bucket uniformly) ----
#define UBKN 98                  // ceil(100000/1024)
#define IBKN 98                  // ceil(50000/512)
#define NBK  (UBKN + IBKN)       // 196
#define FIFO_CAP 32
#define NBLK1 1024
#define EROUND 512               // edges per round (2 per thread)
#define CHUNK ((N_EDGES / 2 + NBLK1 - 1) / NBLK1)  // 1954
#define BIN_CAP 24576            // 96KB LDS image; max bucket ~21K edges

typedef int int4v __attribute__((ext_vector_type(4)));

__device__ inline int bucket_of(int n) {
  return (n < USER_COUNT) ? (n >> 10) : (UBKN + ((n - USER_COUNT) >> 9));
}
__device__ inline int bucket_lo(int b) {
  return (b < UBKN) ? (b << 10) : (USER_COUNT + ((b - UBKN) << 9));
}
__device__ inline int bucket_hi(int b) {
  int hi = (b < UBKN) ? ((b + 1) << 10) : (USER_COUNT + ((b - UBKN + 1) << 9));
  int cap = (b < UBKN) ? USER_COUNT : N_NODES;
  return hi < cap ? hi : cap;
}
// pack (local-row-in-bucket [10b], neighbor node [18b]) into one u32
__device__ inline uint32_t pack_pair(int a, int bnode) {
  const int lrow = (a < USER_COUNT) ? (a & 1023) : ((a - USER_COUNT) & 511);
  return ((uint32_t)lrow << 18) | (uint32_t)bnode;
}

// ---- JAX threefry-2x32 (20 rounds), bit-exact ----
__host__ __device__ inline void threefry2x32(uint32_t k0, uint32_t k1,
                                             uint32_t& x0, uint32_t& x1) {
  const uint32_t ks2 = k0 ^ k1 ^ 0x1BD11BDAu;
  x0 += k0; x1 += k1;
#define TF_ROT(r) { x0 += x1; x1 = (x1 << (r)) | (x1 >> (32 - (r))); x1 ^= x0; }
  TF_ROT(13) TF_ROT(15) TF_ROT(26) TF_ROT(6)
  x0 += k1;  x1 += ks2 + 1u;
  TF_ROT(17) TF_ROT(29) TF_ROT(16) TF_ROT(24)
  x0 += ks2; x1 += k0 + 2u;
  TF_ROT(13) TF_ROT(15) TF_ROT(26) TF_ROT(6)
  x0 += k0;  x1 += k1 + 3u;
  TF_ROT(17) TF_ROT(29) TF_ROT(16) TF_ROT(24)
  x0 += k1;  x1 += ks2 + 4u;
  TF_ROT(13) TF_ROT(15) TF_ROT(26) TF_ROT(6)
  x0 += ks2; x1 += k0 + 5u;
#undef TF_ROT
}

// Bucket histogram: 196 LDS bins per block, one global atomic per bin per
// block. (R13 lesson: 8M global atomics = 160us of coherence traffic.)
__global__ __launch_bounds__(256) void k_bkhist(const int* __restrict__ rows,
                                                const int* __restrict__ cols,
                                                int* __restrict__ bkcnt) {
  __shared__ int h[NBK];
  for (int i = threadIdx.x; i < NBK; i += 256) h[i] = 0;
  __syncthreads();
  const int stride = gridDim.x * blockDim.x;
  for (int e = blockIdx.x * blockDim.x + threadIdx.x; e < N_EDGES / 2; e += stride) {
    const int r = __builtin_nontemporal_load(rows + e);
    const int c = __builtin_nontemporal_load(cols + e);
    atomicAdd(&h[bucket_of(r)], 1);
    atomicAdd(&h[bucket_of(c)], 1);
  }
  __syncthreads();
  for (int i = threadIdx.x; i < NBK; i += 256)
    if (h[i]) atomicAdd(&bkcnt[i], h[i]);
}

// 1-wave exclusive scan of bucket counts -> bstart[0..NBK] and bcur init.
__global__ void k_bkscan(const int* __restrict__ bkcnt, int* __restrict__ bstart,
                         int* __restrict__ bcur) {
  const int lane = threadIdx.x; // blockDim = 64
  int carry = 0;
  for (int base = 0; base < NBK; base += 64) {
    const int idx = base + lane;
    int v = (idx < NBK) ? bkcnt[idx] : 0;
    int inc = v;
#pragma unroll
    for (int s = 1; s < 64; s <<= 1) { int t = __shfl_up(inc, s); if (lane >= s) inc += t; }
    if (idx < NBK) { bstart[idx] = inc - v + carry; bcur[idx] = inc - v + carry; }
    carry += __shfl(inc, 63);
  }
  if (lane == 0) bstart[NBK] = carry;   // == N_EDGES
}

// Pass 1: stream first 2M (r,c); insert packed (r->bkt(r)) and (c->bkt(c))
// into LDS ring-FIFOs; flush 16-pair (64B) contiguous runs via one
// global-cursor atomic per run. Coalesced writes beat the no-write-allocate
// L2 (scattered 4B stores cost a full line each — R6/R9/R11).
__global__ __launch_bounds__(256) void k_p1(const int* __restrict__ rows,
                                            const int* __restrict__ cols,
                                            int* __restrict__ bcur,
                                            uint32_t* __restrict__ pairs) {
  __shared__ uint32_t fifo[NBK * FIFO_CAP];
  __shared__ int cnt[NBK], tail[NBK], rc[NBK];
  __shared__ int wlB[NBK], wlG[NBK], wlT[NBK], wlM[NBK];
  __shared__ unsigned char ovf[NBK];
  __shared__ int wlN;
  const int tid = threadIdx.x;
  for (int b = tid; b < NBK; b += 256) { cnt[b] = 0; tail[b] = 0; }
  const int eStart = blockIdx.x * CHUNK;
  const int eEnd = (eStart + CHUNK < N_EDGES / 2) ? eStart + CHUNK : N_EDGES / 2;
  for (int base = eStart; base < eEnd; base += EROUND) {
    int rr[2], cc2[2];
    bool val[2];
#pragma unroll
    for (int q = 0; q < 2; ++q) {
      const int e = base + q * 256 + tid;
      val[q] = e < eEnd;
      if (val[q]) { rr[q] = __builtin_nontemporal_load(rows + e);
                    cc2[q] = __builtin_nontemporal_load(cols + e); }
    }
    for (int b = tid; b < NBK; b += 256) rc[b] = 0;
    if (tid == 0) wlN = 0;
    __syncthreads();
#pragma unroll
    for (int q = 0; q < 2; ++q)
      if (val[q]) { atomicAdd(&rc[bucket_of(rr[q])], 1);
                    atomicAdd(&rc[bucket_of(cc2[q])], 1); }
    __syncthreads();
    for (int b = tid; b < NBK; b += 256)
      ovf[b] = (cnt[b] - tail[b] + rc[b] > FIFO_CAP) ? 1 : 0;
    __syncthreads();
#pragma unroll
    for (int q = 0; q < 2; ++q) {
      if (val[q]) {
#pragma unroll
        for (int dir = 0; dir < 2; ++dir) {
          const int a = dir ? cc2[q] : rr[q], bnode = dir ? rr[q] : cc2[q];
          const int bb = bucket_of(a);
          const uint32_t pk = pack_pair(a, bnode);
          if (ovf[bb]) {
            int g = atomicAdd(&bcur[bb], 1);
            pairs[g] = pk;                              // rare spill
          } else {
            int idx = atomicAdd(&cnt[bb], 1);
            fifo[bb * FIFO_CAP + (idx & (FIFO_CAP - 1))] = pk;
          }
        }
      }
    }
    __syncthreads();
    for (int b = tid; b < NBK; b += 256) {
      int m = (cnt[b] - tail[b]) & ~15;                 // 0,16,32
      if (m > 0) {
        int g = atomicAdd(&bcur[b], m);
        int w = atomicAdd(&wlN, 1);
        wlB[w] = b; wlG[w] = g; wlT[w] = tail[b]; wlM[w] = m;
        tail[b] += m;
      }
    }
    __syncthreads();
    const int nw = wlN;
    for (int j = tid; j < nw * FIFO_CAP; j += 256) {
      const int wi = j / FIFO_CAP, k = j % FIFO_CAP;
      if (k < wlM[wi]) {
        const int b = wlB[wi];
        const int s = (wlT[wi] + k) & (FIFO_CAP - 1);
        pairs[wlG[wi] + k] = fifo[b * FIFO_CAP + s];
      }
    }
    __syncthreads();
  }
  // final drain (<=31 pairs per bucket)
  for (int b = tid; b < NBK; b += 256) {
    const int m = cnt[b] - tail[b];
    if (m > 0) {
      int g = atomicAdd(&bcur[b], m);
      for (int k = 0; k < m; ++k)
        pairs[g + k] = fifo[b * FIFO_CAP + ((tail[b] + k) & (FIFO_CAP - 1))];
    }
  }
}

// Pass 2: one block per bucket. Count lrow in LDS -> per-node deg/dis and
// inclusive-end ptr via block scan (bucket pair-region base == global row
// prefix), then bin into LDS image and write ecol coalesced.
__global__ __launch_bounds__(256) void k_bin2(const int* __restrict__ bstart,
                                              const uint32_t* __restrict__ pairs,
                                              int* __restrict__ ecol,
                                              int* __restrict__ ptr,
                                              int* __restrict__ deg,
                                              float* __restrict__ dis) {
  __shared__ int img[BIN_CAP];
  __shared__ int cnt[1024];
  __shared__ int cur[1024];
  __shared__ int ws[4];
  const int b = blockIdx.x;
  const int tid = threadIdx.x;
  const int lane = tid & 63, wid = tid >> 6;
  const int lo = bucket_lo(b), hi = bucket_hi(b), nn = hi - lo;
  const int base = bstart[b];
  const int n = bstart[b + 1] - base;
  for (int i = tid; i < 1024; i += 256) cnt[i] = 0;
  __syncthreads();
  for (int j = tid; j < n; j += 256)
    atomicAdd(&cnt[pairs[base + j] >> 18], 1);
  __syncthreads();
  // block exclusive scan over cnt[0..1024): 4 values/thread + wave/block scan
  const int i0 = tid * 4;
  const int v0 = cnt[i0], v1 = cnt[i0 + 1], v2 = cnt[i0 + 2], v3 = cnt[i0 + 3];
  const int s4 = v0 + v1 + v2 + v3;
  int inc = s4;
#pragma unroll
  for (int s = 1; s < 64; s <<= 1) { int t = __shfl_up(inc, s); if (lane >= s) inc += t; }
  if (lane == 63) ws[wid] = inc;
  __syncthreads();
  int woff = 0;
  for (int w = 0; w < wid; ++w) woff += ws[w];
  int pre = woff + inc - s4;
  const int vv[4] = { v0, v1, v2, v3 };
#pragma unroll
  for (int k = 0; k < 4; ++k) {
    const int i = i0 + k;
    if (i < nn) {
      const int node = lo + i;
      cur[i] = pre;
      deg[node] = vv[k];
      dis[node] = 1.0f / sqrtf((float)(vv[k] > 0 ? vv[k] : 1));
      ptr[node] = base + pre + vv[k];        // inclusive end of row
    }
    pre += vv[k];
  }
  __syncthreads();
  for (int j = tid; j < n; j += 256) {
    const uint32_t pr = pairs[base + j];
    const int p = atomicAdd(&cur[pr >> 18], 1);
    img[p] = (int)(pr & 0x3FFFFu);
  }
  __syncthreads();
  for (int j = tid; j < n; j += 256) ecol[base + j] = img[j];
}

// One wave per output row, Z-iteration gather-sum; 32 gathers in flight.
// fp32 throughout (R8: narrow Z flips sign(ego) -> fails). All shapes tried
// plateau at ~3.3-3.7 TB/s L2-fill for the random gather; time ~= FETCH/BW.
// MODE 0: clean, gather Z.  MODE 1: noisy, gather Z.
// MODE 2: FIRST layer — gather raw ue/ie rows and apply dis[c] in the FMA
//         (kills the k_init round-trip; dis is L2-resident).
template <int MODE>
__global__ __launch_bounds__(256) void k_spmm(const int* __restrict__ ptr,
                                              const int* __restrict__ ecol,
                                              const float* __restrict__ dis,
                                              const float* __restrict__ Z,
                                              const float* __restrict__ ie,
                                              float* __restrict__ Zout,
                                              uint32_t k0, uint32_t k1) {
  const int w = (blockIdx.x * blockDim.x + threadIdx.x) >> 6;
  const int lane = threadIdx.x & 63;
  if (w >= N_NODES) return;
  const int g   = lane >> 4;
  const int sub = lane & 15;
  const int e1 = ptr[w];
  const int e0 = (w > 0) ? ptr[w - 1] : 0;
  const float4* __restrict__ Z4 = (const float4*)Z;   // MODE 2: user_emb
  const float4* __restrict__ I4 = (const float4*)ie;  // MODE 2: item_emb

  float ax = 0.f, ay = 0.f, az = 0.f, aq = 0.f;
  for (int j = e0 + g; j < e1; j += 32) {
    int  cc[8];
    bool ok[8];
#pragma unroll
    for (int s = 0; s < 8; ++s) {
      const int js = j + 4 * s;
      ok[s] = js < e1;
      cc[s] = __builtin_nontemporal_load(ecol + (ok[s] ? js : j));
    }
    float4 xv[8];
    float  dd[8];
#pragma unroll
    for (int s = 0; s < 8; ++s) {
      if (MODE == 2) {
        const float4* base = (cc[s] < USER_COUNT)
            ? Z4 + (size_t)cc[s] * 16
            : I4 + (size_t)(cc[s] - USER_COUNT) * 16;
        xv[s] = base[sub];
        dd[s] = dis[cc[s]];
      } else {
        xv[s] = Z4[cc[s] * 16 + sub];
      }
    }
#pragma unroll
    for (int s = 0; s < 8; ++s) {
      const float m = ok[s] ? ((MODE == 2) ? dd[s] : 1.f) : 0.f;
      ax = fmaf(m, xv[s].x, ax); ay = fmaf(m, xv[s].y, ay);
      az = fmaf(m, xv[s].z, az); aq = fmaf(m, xv[s].w, aq);
    }
  }
  ax += __shfl_xor(ax, 16); ax += __shfl_xor(ax, 32);
  ay += __shfl_xor(ay, 16); ay += __shfl_xor(ay, 32);
  az += __shfl_xor(az, 16); az += __shfl_xor(az, 32);
  aq += __shfl_xor(aq, 16); aq += __shfl_xor(aq, 32);

  const float dw = dis[w];
  float z0, z1, z2, z3;
  if (MODE == 1) {
    float v0 = dw * ax, v1 = dw * ay, v2 = dw * az, v3 = dw * aq;
    uint32_t t0 = 0u, t1 = (uint32_t)(w * EMB + sub * 4 + g);
    threefry2x32(k0, k1, t0, t1);
    const uint32_t bits = t0 ^ t1;
    const float u = __uint_as_float((bits >> 9) | 0x3f800000u) - 1.0f;
    float ss = u * u;
#pragma unroll
    for (int s = 1; s < 64; s <<= 1) ss += __shfl_xor(ss, s);
    const float inv = 1.0f / fmaxf(sqrtf(ss), 1e-12f);
    const float u0 = __shfl(u, sub);
    const float u1 = __shfl(u, 16 + sub);
    const float u2 = __shfl(u, 32 + sub);
    const float u3 = __shfl(u, 48 + sub);
    const float e = EPS_F * inv;
    v0 = fmaf(((v0 > 0.f) ? 1.f : ((v0 < 0.f) ? -1.f : 0.f)) * u0, e, v0);
    v1 = fmaf(((v1 > 0.f) ? 1.f : ((v1 < 0.f) ? -1.f : 0.f)) * u1, e, v1);
    v2 = fmaf(((v2 > 0.f) ? 1.f : ((v2 < 0.f) ? -1.f : 0.f)) * u2, e, v2);
    v3 = fmaf(((v3 > 0.f) ? 1.f : ((v3 < 0.f) ? -1.f : 0.f)) * u3, e, v3);
    z0 = dw * v0; z1 = dw * v1; z2 = dw * v2; z3 = dw * v3;
  } else {
    const float d2 = dw * dw;
    z0 = d2 * ax; z1 = d2 * ay; z2 = d2 * az; z3 = d2 * aq;
  }
  {
    if (g == 0) {
      float4 r; r.x = z0; r.y = z1; r.z = z2; r.w = z3;
      ((float4*)Zout)[w * 16 + sub] = r;
    }
  }
}

// Final noisy layer (k=2): only batch rows needed -> fused spmm+noise+mean.
__global__ __launch_bounds__(256) void k_spmm_last(const int* __restrict__ ptr,
                                                   const int* __restrict__ ecol,
                                                   const float* __restrict__ dis,
                                                   const float* __restrict__ Z,
                                                   const int* __restrict__ users,
                                                   const int* __restrict__ items,
                                                   float* __restrict__ out_u,
                                                   float* __restrict__ out_i,
                                                   uint32_t k0, uint32_t k1) {
  const int b = (blockIdx.x * blockDim.x + threadIdx.x) >> 6;
  const int lane = threadIdx.x & 63;
  if (b >= 2 * BATCH) return;
  const int g   = lane >> 4;
  const int sub = lane & 15;
  int w; float* dst;
  if (b < BATCH) { w = users[b];                      dst = out_u + (size_t)b * EMB; }
  else           { w = USER_COUNT + items[b - BATCH]; dst = out_i + (size_t)(b - BATCH) * EMB; }
  const int e1 = ptr[w];
  const int e0 = (w > 0) ? ptr[w - 1] : 0;
  const float4* __restrict__ Z4 = (const float4*)Z;

  float ax = 0.f, ay = 0.f, az = 0.f, aq = 0.f;
  for (int j = e0 + g; j < e1; j += 32) {
    int  cc[8];
    bool ok[8];
#pragma unroll
    for (int s = 0; s < 8; ++s) {
      const int js = j + 4 * s;
      ok[s] = js < e1;
      cc[s] = __builtin_nontemporal_load(ecol + (ok[s] ? js : j));
    }
    float4 xv[8];
#pragma unroll
    for (int s = 0; s < 8; ++s) xv[s] = Z4[cc[s] * 16 + sub];
#pragma unroll
    for (int s = 0; s < 8; ++s) {
      const float m = ok[s] ? 1.f : 0.f;
      ax = fmaf(m, xv[s].x, ax); ay = fmaf(m, xv[s].y, ay);
      az = fmaf(m, xv[s].z, az); aq = fmaf(m, xv[s].w, aq);
    }
  }
  ax += __shfl_xor(ax, 16); ax += __shfl_xor(ax, 32);
  ay += __shfl_xor(ay, 16); ay += __shfl_xor(ay, 32);
  az += __shfl_xor(az, 16); az += __shfl_xor(az, 32);
  aq += __shfl_xor(aq, 16); aq += __shfl_xor(aq, 32);

  const float dw = dis[w];
  float v0 = dw * ax, v1 = dw * ay, v2 = dw * az, v3 = dw * aq;
  uint32_t t0 = 0u, t1 = (uint32_t)(w * EMB + sub * 4 + g);
  threefry2x32(k0, k1, t0, t1);
  const uint32_t bits = t0 ^ t1;
  const float u = __uint_as_float((bits >> 9) | 0x3f800000u) - 1.0f;
  float ss = u * u;
#pragma unroll
  for (int s = 1; s < 64; s <<= 1) ss += __shfl_xor(ss, s);
  const float inv = 1.0f / fmaxf(sqrtf(ss), 1e-12f);
  const float u0 = __shfl(u, sub);
  const float u1 = __shfl(u, 16 + sub);
  const float u2 = __shfl(u, 32 + sub);
  const float u3 = __shfl(u, 48 + sub);
  const float e = EPS_F * inv;
  v0 = fmaf(((v0 > 0.f) ? 1.f : ((v0 < 0.f) ? -1.f : 0.f)) * u0, e, v0);
  v1 = fmaf(((v1 > 0.f) ? 1.f : ((v1 < 0.f) ? -1.f : 0.f)) * u1, e, v1);
  v2 = fmaf(((v2 > 0.f) ? 1.f : ((v2 < 0.f) ? -1.f : 0.f)) * u2, e, v2);
  v3 = fmaf(((v3 > 0.f) ? 1.f : ((v3 < 0.f) ? -1.f : 0.f)) * u3, e, v3);

  if (g == 0) {
    float4 o = ((float4*)dst)[sub];
    o.x += v0 * (1.0f / 3.0f); o.y += v1 * (1.0f / 3.0f);
    o.z += v2 * (1.0f / 3.0f); o.w += v3 * (1.0f / 3.0f);
    ((float4*)dst)[sub] = o;
  }
}

// gather batch rows from Z, recovering ego = Z * sqrt(max(deg,1))
__global__ __launch_bounds__(256) void k_gather(const float* __restrict__ Z,
                                                const int* __restrict__ deg,
                                                const int* __restrict__ users,
                                                const int* __restrict__ items,
                                                float* __restrict__ out_u,
                                                float* __restrict__ out_i,
                                                float* __restrict__ cl_u,
                                                float* __restrict__ cl_i,
                                                float scale, int init) {
  const int w = (blockIdx.x * blockDim.x + threadIdx.x) >> 6;
  const int lane = threadIdx.x & 63;
  if (w >= 2 * BATCH) return;
  int src; float* dst; float* dst2;
  if (w < BATCH) {
    src = users[w];               dst = out_u + w * EMB;
    dst2 = cl_u ? cl_u + w * EMB : nullptr;
  } else {
    int q = w - BATCH;
    src = USER_COUNT + items[q];  dst = out_i + q * EMB;
    dst2 = cl_i ? cl_i + q * EMB : nullptr;
  }
  const int d = deg[src];
  const float rdis = sqrtf((float)(d > 0 ? d : 1));
  float raw = Z[(size_t)src * EMB + lane] * rdis;
  float v = raw * scale;
  dst[lane] = init ? v : (dst[lane] + v);
  if (dst2) dst2[lane] = raw;
}

extern "C" void kernel_launch(void* const* d_in, const int* in_sizes, int n_in,
                              void* d_out, int out_size, void* d_ws, size_t ws_size,
                              hipStream_t stream) {
  const float* user_emb = (const float*)d_in[0];
  const float* item_emb = (const float*)d_in[1];
  // d_in[2] = vals: unused, recomputed bit-identically from degrees
  const int* rows  = (const int*)d_in[3];
  const int* cols  = (const int*)d_in[4];
  const int* users = (const int*)d_in[5];
  const int* items = (const int*)d_in[6];

  float* X   = (float*)d_ws;                       // 9.6M f32 (Z ping)
  float* Y   = X + (size_t)N_NODES * EMB;          // 9.6M f32 (Z pong)
  int*   deg = (int*)(Y + (size_t)N_NODES * EMB);  // 150k
  int*   ptr = deg + N_NODES;                      // 150k
  float* dis = (float*)(ptr + N_NODES);            // 150k
  int*   ecol = (int*)(dis + N_NODES);             // 4M
  int*   bkcnt = ecol + N_EDGES;                   // 196
  int*   bstart = bkcnt + 256;                     // 197
  int*   bcur = bstart + 256;                      // 196
  uint32_t* pairs = (uint32_t*)X;                  // 4M u32, aliases X (dead
                                                   // until first spmm output)

  float* out  = (float*)d_out;
  float* u_all = out;
  float* i_all = out + (size_t)BATCH * EMB;
  float* u_tr  = out + (size_t)2 * BATCH * EMB;
  float* i_tr  = out + (size_t)3 * BATCH * EMB;
  float* u_cl  = out + (size_t)4 * BATCH * EMB;
  float* i_cl  = out + (size_t)5 * BATCH * EMB;

  // ---- build CSR: bucket-hist -> scan -> LDS-staged counting sort ----
  hipMemsetAsync(bkcnt, 0, sizeof(int) * 256, stream);
  k_bkhist<<<1024, 256, 0, stream>>>(rows, cols, bkcnt);
  k_bkscan<<<1, 64, 0, stream>>>(bkcnt, bstart, bcur);
  k_p1<<<NBLK1, 256, 0, stream>>>(rows, cols, bcur, pairs);
  k_bin2<<<NBK, 256, 0, stream>>>(bstart, pairs, ecol, ptr, deg, dis);

  const int spmm_grid = (N_NODES * EMB + 255) / 256; // 37500
  const int gat_grid  = (2 * BATCH * EMB + 255) / 256; // 2048

  // ---- layer 1 (clean): gather raw embeddings with dis[c] fused; no k_init.
  // Writes X (pairs alias dead after k_bin2). ----
  k_spmm<2><<<spmm_grid, 256, 0, stream>>>(ptr, ecol, dis, user_emb, item_emb,
                                           X, 0u, 0u);
  k_gather<<<gat_grid, 256, 0, stream>>>(X, deg, users, items, u_all, i_all,
                                         nullptr, nullptr, 1.0f / 3.0f, 1);

  // ---- layers 2,3 (clean), mean-gather into outputs 0,1 ----
  float* src = X; float* dst = Y;
  for (int l = 1; l < 3; ++l) {
    k_spmm<0><<<spmm_grid, 256, 0, stream>>>(ptr, ecol, dis, src, nullptr,
                                             dst, 0u, 0u);
    k_gather<<<gat_grid, 256, 0, stream>>>(dst, deg, users, items, u_all, i_all,
                                           nullptr, nullptr, 1.0f / 3.0f, 0);
    float* t = src; src = dst; dst = t;
  }

  // ---- noisy layers k=0,1 full-width; k=2 batch-rows-only fused ----
  for (int k = 0; k < 2; ++k) {
    uint32_t f0 = 0u, f1 = (uint32_t)k;      // fold_in(key(42), k)
    threefry2x32(0u, 42u, f0, f1);
    k_spmm<1><<<spmm_grid, 256, 0, stream>>>(ptr, ecol, dis, src, nullptr,
                                             dst, f0, f1);
    k_gather<<<gat_grid, 256, 0, stream>>>(dst, deg, users, items, u_tr, i_tr,
                                           (k == 0) ? u_cl : nullptr,
                                           (k == 0) ? i_cl : nullptr,
                                           1.0f / 3.0f, k == 0);
    float* t = src; src = dst; dst = t;
  }
  {
    uint32_t f0 = 0u, f1 = 2u;               // fold_in(key(42), 2)
    threefry2x32(0u, 42u, f0, f1);
    k_spmm_last<<<gat_grid, 256, 0, stream>>>(ptr, ecol, dis, src, users, items,
                                              u_tr, i_tr, f0, f1);
  }
}